// Round 13
// baseline (215.960 us; speedup 1.0000x reference)
//
#include <hip/hip_runtime.h>
#include <math.h>

// Problem constants
constexpr int Bn = 4;
constexpr int Tn = 2048;
constexpr int Dn = 512;
constexpr int Hn = 8;
constexpr int HDn = 64;       // head dim
constexpr int Fn = 2048;
constexpr int WIN = 128;
constexpr float EPS = 1e-5f;
constexpr int Mrows = Bn * Tn;          // 8192
constexpr int QKVD = 3 * Dn;            // 1536

using short8 = __attribute__((ext_vector_type(8))) short;
using f32x4  = __attribute__((ext_vector_type(4))) float;

// fp32 -> bf16 (RNE) as raw short
__device__ __forceinline__ short f2bf(float f) {
    unsigned u = __float_as_uint(f);
    unsigned r = (u + 0x7FFFu + ((u >> 16) & 1u)) >> 16;
    return (short)r;
}
__device__ __forceinline__ float bf2f(short s) {
    return __uint_as_float(((unsigned)(unsigned short)s) << 16);
}

// tanh-form GELU (max abs dev from exact < 1e-3; threshold is 0.104)
__device__ __forceinline__ float gelu_fast(float v) {
    float u = 1.5957691216f * v * (1.0f + 0.044715f * v * v);
    float t = 1.0f - 2.0f / (__expf(u) + 1.0f);
    return 0.5f * v * (1.0f + t);
}

// async 16B global -> LDS (wave-uniform LDS base; HW scatters lane i at base+16*i)
__device__ __forceinline__ void async16(const short* g, short* l) {
    __builtin_amdgcn_global_load_lds(
        (const __attribute__((address_space(1))) void*)g,
        (__attribute__((address_space(3))) void*)l,
        16, 0, 0);
}

// ---------------- LN body, f32 input (wave-local, one row of 512) ----------------
__device__ __forceinline__ void ln_row(const float* __restrict__ xrow,
                                       const float* __restrict__ g,
                                       const float* __restrict__ b,
                                       short* __restrict__ yrow, int lane)
{
    const float4* xr = (const float4*)xrow;
    float4 v0 = xr[lane];
    float4 v1 = xr[lane + 64];
    float s = v0.x + v0.y + v0.z + v0.w + v1.x + v1.y + v1.z + v1.w;
#pragma unroll
    for (int off = 32; off >= 1; off >>= 1) s += __shfl_xor(s, off, 64);
    float mu = s * (1.0f / Dn);
    float d0x = v0.x - mu, d0y = v0.y - mu, d0z = v0.z - mu, d0w = v0.w - mu;
    float d1x = v1.x - mu, d1y = v1.y - mu, d1z = v1.z - mu, d1w = v1.w - mu;
    float q = d0x*d0x + d0y*d0y + d0z*d0z + d0w*d0w
            + d1x*d1x + d1y*d1y + d1z*d1z + d1w*d1w;
#pragma unroll
    for (int off = 32; off >= 1; off >>= 1) q += __shfl_xor(q, off, 64);
    float inv = rsqrtf(q * (1.0f / Dn) + EPS);
    const float4* gr = (const float4*)g;
    const float4* br = (const float4*)b;
    float4 g0 = gr[lane], g1 = gr[lane + 64];
    float4 b0 = br[lane], b1 = br[lane + 64];
    short4 a0, a1;
    a0.x = f2bf(d0x * inv * g0.x + b0.x);
    a0.y = f2bf(d0y * inv * g0.y + b0.y);
    a0.z = f2bf(d0z * inv * g0.z + b0.z);
    a0.w = f2bf(d0w * inv * g0.w + b0.w);
    a1.x = f2bf(d1x * inv * g1.x + b1.x);
    a1.y = f2bf(d1y * inv * g1.y + b1.y);
    a1.z = f2bf(d1z * inv * g1.z + b1.z);
    a1.w = f2bf(d1w * inv * g1.w + b1.w);
    short4* yr = (short4*)yrow;
    yr[lane] = a0;
    yr[lane + 64] = a1;
}

// ---------------- prep: weight cvt (blocks 0..3071) + LN1 (blocks 3072..5119) -------
__global__ __launch_bounds__(256) void prep_kernel(const float* __restrict__ s0,
                                                   const float* __restrict__ s1,
                                                   const float* __restrict__ s2,
                                                   const float* __restrict__ s3,
                                                   short* __restrict__ d0,
                                                   short* __restrict__ d1,
                                                   short* __restrict__ d2,
                                                   short* __restrict__ d3,
                                                   const float* __restrict__ x,
                                                   const float* __restrict__ ln1_g,
                                                   const float* __restrict__ ln1_b,
                                                   short* __restrict__ x2)
{
    int bid = blockIdx.x;
    if (bid < 3072) {
        int i = bid * 256 + threadIdx.x;
        const float* src; short* dst; int j;
        if (i < 196608)      { src = s0; dst = d0; j = i; }
        else if (i < 262144) { src = s1; dst = d1; j = i - 196608; }
        else if (i < 524288) { src = s2; dst = d2; j = i - 262144; }
        else                 { src = s3; dst = d3; j = i - 524288; }
        float4 v = ((const float4*)src)[j];
        short4 o;
        o.x = f2bf(v.x); o.y = f2bf(v.y); o.z = f2bf(v.z); o.w = f2bf(v.w);
        ((short4*)dst)[j] = o;
    } else {
        int row = (bid - 3072) * 4 + (threadIdx.x >> 6);
        int lane = threadIdx.x & 63;
        ln_row(x + (size_t)row * Dn, ln1_g, ln1_b, x2 + (size_t)row * Dn, lane);
    }
}

// ---------------- LN2: bf16 input (res1), bf16 output; one wave per row -------------
__global__ __launch_bounds__(256) void ln2_kernel(const short* __restrict__ xh,
                                                  const float* __restrict__ g,
                                                  const float* __restrict__ b,
                                                  short* __restrict__ y)
{
    int row = blockIdx.x * 4 + (threadIdx.x >> 6);
    int lane = threadIdx.x & 63;
    const short* xrow = xh + (size_t)row * Dn;
    short8 v = *(const short8*)(xrow + lane * 8);
    float f[8];
#pragma unroll
    for (int k = 0; k < 8; ++k) f[k] = bf2f(v[k]);
    float s = 0.f;
#pragma unroll
    for (int k = 0; k < 8; ++k) s += f[k];
#pragma unroll
    for (int off = 32; off >= 1; off >>= 1) s += __shfl_xor(s, off, 64);
    float mu = s * (1.0f / Dn);
    float q = 0.f;
#pragma unroll
    for (int k = 0; k < 8; ++k) { float d = f[k] - mu; q += d * d; }
#pragma unroll
    for (int off = 32; off >= 1; off >>= 1) q += __shfl_xor(q, off, 64);
    float inv = rsqrtf(q * (1.0f / Dn) + EPS);
    const float4* gr = (const float4*)g;
    const float4* br = (const float4*)b;
    float4 g0 = gr[2 * lane], g1 = gr[2 * lane + 1];
    float4 b0 = br[2 * lane], b1 = br[2 * lane + 1];
    float gg[8] = {g0.x, g0.y, g0.z, g0.w, g1.x, g1.y, g1.z, g1.w};
    float bb[8] = {b0.x, b0.y, b0.z, b0.w, b1.x, b1.y, b1.z, b1.w};
    short8 o;
#pragma unroll
    for (int k = 0; k < 8; ++k) o[k] = f2bf((f[k] - mu) * inv * gg[k] + bb[k]);
    *(short8*)(y + (size_t)row * Dn + lane * 8) = o;
}

// ------- gemm_res: 64x128 tile, BK=64, double-buffered, 2 blocks/CU ----
// RIN: 0 = resid f32, 1 = resid bf16. OUT: 0 = f32 direct, 1 = bf16 via LDS repack.
template <int RIN, int OUT>
__global__ __launch_bounds__(256) void gemm_res(const short* __restrict__ A,
                                                const short* __restrict__ Bw,
                                                const float* __restrict__ bias,
                                                const void* __restrict__ resid,
                                                void* __restrict__ Cout,
                                                int M, int N, int K)
{
    constexpr int BK = 64;
    constexpr int ABUF = 64 * BK;               // 4096 shorts
    constexpr int BBUF = 128 * BK;              // 8192 shorts
    __shared__ short SMEM[2 * (ABUF + BBUF)];   // 48 KB
    short* Asb = SMEM;
    short* Bsb = SMEM + 2 * ABUF;

    int tid = threadIdx.x;
    int w = tid >> 6, lane = tid & 63;
    int wr = w >> 1, wc = w & 1;                // wave tile 32m x 64n
    int nN = N >> 7;
    int bid = blockIdx.x;
    int xcd = bid & 7, sq = bid >> 3;
    int mi = xcd + 8 * (sq / nN);
    int ni = sq % nN;
    int m0 = mi * 64, n0 = ni * 128;
    int quad = lane >> 4, l16 = lane & 15;

    f32x4 zero = {0.f, 0.f, 0.f, 0.f};
    f32x4 acc[2][4];
#pragma unroll
    for (int i = 0; i < 2; ++i)
#pragma unroll
        for (int j = 0; j < 4; ++j) acc[i][j] = zero;

    int rl = lane >> 3;                          // 0..7
    int ch = lane & 7;
    const short* Ag[2];
    const short* Bg[4];
    int aOff[2], bOff[4];
#pragma unroll
    for (int s = 0; s < 2; ++s) {
        int rowl = w * 16 + s * 8 + rl;
        int csw = (ch ^ (rowl & 7)) * 8;
        Ag[s] = A + (size_t)(m0 + rowl) * K + csw;
        aOff[s] = (w * 16 + s * 8) * BK;
    }
#pragma unroll
    for (int s = 0; s < 4; ++s) {
        int rowl = w * 32 + s * 8 + rl;
        int csw = (ch ^ (rowl & 7)) * 8;
        Bg[s] = Bw + (size_t)(n0 + rowl) * K + csw;
        bOff[s] = (w * 32 + s * 8) * BK;
    }

    auto stage = [&](int kt, int pp) {
#pragma unroll
        for (int s = 0; s < 2; ++s)
            async16(Ag[s] + kt, Asb + pp * ABUF + aOff[s]);
#pragma unroll
        for (int s = 0; s < 4; ++s)
            async16(Bg[s] + kt, Bsb + pp * BBUF + bOff[s]);
    };

    stage(0, 0);
    int p = 0;
    for (int kt = 0; kt < K; kt += BK) {
        __syncthreads();
        if (kt + BK < K) stage(kt + BK, p ^ 1);
        short8 aF[2][2], bF[2][4];
#pragma unroll
        for (int kk = 0; kk < 2; ++kk) {
#pragma unroll
            for (int i = 0; i < 2; ++i) {
                int ra = wr * 32 + i * 16 + l16;
                int cs = ((kk * 4 + quad) ^ (ra & 7)) * 8;
                aF[kk][i] = *(const short8*)(Asb + p * ABUF + ra * BK + cs);
            }
#pragma unroll
            for (int j = 0; j < 4; ++j) {
                int rb = wc * 64 + j * 16 + l16;
                int cs = ((kk * 4 + quad) ^ (rb & 7)) * 8;
                bF[kk][j] = *(const short8*)(Bsb + p * BBUF + rb * BK + cs);
            }
        }
#pragma unroll
        for (int kk = 0; kk < 2; ++kk)
#pragma unroll
            for (int i = 0; i < 2; ++i)
#pragma unroll
                for (int j = 0; j < 4; ++j)
                    acc[i][j] = __builtin_amdgcn_mfma_f32_16x16x32_bf16(
                        aF[kk][i], bF[kk][j], acc[i][j], 0, 0, 0);
        p ^= 1;
    }

    const float* rf = (const float*)resid;
    const short* rh = (const short*)resid;

    if constexpr (OUT == 0) {
        float* Cf = (float*)Cout;
#pragma unroll
        for (int j = 0; j < 4; ++j) {
            int n = n0 + wc * 64 + j * 16 + l16;
            float bv = bias[n];
#pragma unroll
            for (int i = 0; i < 2; ++i) {
                int mbase = m0 + wr * 32 + i * 16 + quad * 4;
#pragma unroll
                for (int r = 0; r < 4; ++r) {
                    size_t idx = (size_t)(mbase + r) * N + n;
                    float rv = RIN ? bf2f(rh[idx]) : rf[idx];
                    Cf[idx] = acc[i][j][r] + bv + rv;
                }
            }
        }
    } else {
        // bf16 out via LDS repack (full-line short8 stores)
        __syncthreads();
        short* rp = SMEM + w * 6144;             // 32 x 72 needed = 2304
#pragma unroll
        for (int j = 0; j < 4; ++j) {
            int n = n0 + wc * 64 + j * 16 + l16;
            float bv = bias[n];
#pragma unroll
            for (int i = 0; i < 2; ++i) {
                int ml = i * 16 + quad * 4;
#pragma unroll
                for (int r = 0; r < 4; ++r) {
                    size_t idx = (size_t)(m0 + wr * 32 + ml + r) * N + n;
                    float rv = RIN ? bf2f(rh[idx]) : rf[idx];
                    rp[(ml + r) * 72 + j * 16 + l16] = f2bf(acc[i][j][r] + bv + rv);
                }
            }
        }
        short* Cb = (short*)Cout;
#pragma unroll
        for (int it = 0; it < 4; ++it) {
            int row = it * 8 + (lane >> 3);
            int off = (lane & 7) * 8;
            *(short8*)(Cb + (size_t)(m0 + wr * 32 + row) * N + n0 + wc * 64 + off) =
                *(const short8*)(rp + row * 72 + off);
        }
    }
}

// ---------------- QKV GEMM: 64x256 tile, BK=32, wave 32x128; grid 768 = 3/CU --------
// bf16 out into attention layouts (q/k row-major [bh][t][64], v transposed [bh][64][t]).
__global__ __launch_bounds__(256, 3) void gemm_qkv(const short* __restrict__ A,
                                                   const short* __restrict__ Bw,
                                                   const float* __restrict__ bias,
                                                   short* __restrict__ q_out,
                                                   short* __restrict__ k_out,
                                                   short* __restrict__ v_out,
                                                   int M, int N, int K)
{
    constexpr int BK = 32;
    constexpr int ABUF = 64 * BK;               // 2048 shorts
    constexpr int BBUF = 256 * BK;              // 8192 shorts
    __shared__ short SMEM[2 * (ABUF + BBUF)];   // 20480 shorts = 40 KB
    short* Asb = SMEM;
    short* Bsb = SMEM + 2 * ABUF;

    int tid = threadIdx.x;
    int w = tid >> 6, lane = tid & 63;
    int wr = w >> 1, wc = w & 1;                // wave tile 32m x 128n
    int nT = N >> 8;                            // 6
    int bid = blockIdx.x;
    int xcd = bid & 7, sq = bid >> 3;
    int mi = xcd + 8 * (sq / nT);
    int ni = sq % nT;
    int m0 = mi * 64, n0 = ni * 256;
    int quad = lane >> 4, l16 = lane & 15;

    f32x4 zero = {0.f, 0.f, 0.f, 0.f};
    f32x4 acc[2][8];
#pragma unroll
    for (int i = 0; i < 2; ++i)
#pragma unroll
        for (int j = 0; j < 8; ++j) acc[i][j] = zero;

    int rl = lane >> 2;                          // 0..15
    int ch = lane & 3;
    const short* Ag;
    const short* Bg[4];
    int aOff, bOff[4];
    {
        int rowl = w * 16 + rl;
        int csw = (ch ^ ((rowl >> 1) & 3)) * 8;
        Ag = A + (size_t)(m0 + rowl) * K + csw;
        aOff = (w * 16) * BK;
    }
#pragma unroll
    for (int s = 0; s < 4; ++s) {
        int rowl = w * 64 + s * 16 + rl;
        int csw = (ch ^ ((rowl >> 1) & 3)) * 8;
        Bg[s] = Bw + (size_t)(n0 + rowl) * K + csw;
        bOff[s] = (w * 64 + s * 16) * BK;
    }

    auto stage = [&](int kt, int pp) {
        async16(Ag + kt, Asb + pp * ABUF + aOff);
#pragma unroll
        for (int s = 0; s < 4; ++s)
            async16(Bg[s] + kt, Bsb + pp * BBUF + bOff[s]);
    };

    int aoff[2], boff[8];
#pragma unroll
    for (int i = 0; i < 2; ++i) {
        int ra = wr * 32 + i * 16 + l16;
        aoff[i] = ra * BK + (quad ^ ((ra >> 1) & 3)) * 8;
    }
#pragma unroll
    for (int j = 0; j < 8; ++j) {
        int rb = wc * 128 + j * 16 + l16;
        boff[j] = rb * BK + (quad ^ ((rb >> 1) & 3)) * 8;
    }

    stage(0, 0);
    int p = 0;
    for (int kt = 0; kt < K; kt += BK) {
        __syncthreads();
        if (kt + BK < K) stage(kt + BK, p ^ 1);
        short8 aF[2], bF[8];
#pragma unroll
        for (int i = 0; i < 2; ++i)
            aF[i] = *(const short8*)(Asb + p * ABUF + aoff[i]);
#pragma unroll
        for (int j = 0; j < 8; ++j)
            bF[j] = *(const short8*)(Bsb + p * BBUF + boff[j]);
#pragma unroll
        for (int i = 0; i < 2; ++i)
#pragma unroll
            for (int j = 0; j < 8; ++j)
                acc[i][j] = __builtin_amdgcn_mfma_f32_16x16x32_bf16(
                    aF[i], bF[j], acc[i][j], 0, 0, 0);
        p ^= 1;
    }

    __syncthreads();                             // K-loop LDS dead -> repack
    short* rp = SMEM + w * 5120;                 // per-wave slot (5120 shorts)
    float bv[8];
#pragma unroll
    for (int j = 0; j < 8; ++j) bv[j] = bias[n0 + wc * 128 + j * 16 + l16];

    int b = m0 >> 11;
    int ncol0 = n0 + wc * 128;
    int sec = ncol0 >> 9;                        // 0=q 1=k 2=v (128-slice never crosses)
    int h0 = (ncol0 & 511) >> 6;                 // heads h0, h0+1
    int t0 = (m0 & 2047) + wr * 32;

    if (sec == 2) {
        // per phase: one head; transposed rp[d*40 + t_local], stride 40 (80B, 16B-mult)
#pragma unroll
        for (int ph = 0; ph < 2; ++ph) {
#pragma unroll
            for (int j = 4 * ph; j < 4 * ph + 4; ++j) {
                int d = (j - 4 * ph) * 16 + l16;
#pragma unroll
                for (int i = 0; i < 2; ++i)
#pragma unroll
                    for (int r = 0; r < 4; ++r)
                        rp[d * 40 + i * 16 + quad * 4 + r] = f2bf(acc[i][j][r] + bv[j]);
            }
            int bh = b * 8 + h0 + ph;
#pragma unroll
            for (int it = 0; it < 4; ++it) {
                int drow = it * 16 + (lane >> 2);        // 0..63
                int toff = (lane & 3) * 8;               // 0..24
                *(short8*)(v_out + ((size_t)bh * 64 + drow) * 2048 + t0 + toff) =
                    *(const short8*)(rp + drow * 40 + toff);
            }
        }
    } else {
        short* dst = (sec == 0 ? q_out : k_out);
        // rows 32 t x 128 cols (2 heads); rp stride 136 (272B, 16B-mult)
#pragma unroll
        for (int i = 0; i < 2; ++i) {
            int tl = i * 16 + quad * 4;
#pragma unroll
            for (int j = 0; j < 8; ++j)
#pragma unroll
                for (int r = 0; r < 4; ++r)
                    rp[(tl + r) * 136 + j * 16 + l16] = f2bf(acc[i][j][r] + bv[j]);
        }
#pragma unroll
        for (int it = 0; it < 8; ++it) {
            int trow = it * 4 + (lane >> 4);             // 0..31
            int hh = (lane & 15) >> 3;                   // head select
            int off = (lane & 7) * 8;                    // d chunk
            int bh = b * 8 + h0 + hh;
            *(short8*)(dst + ((size_t)bh * 2048 + t0 + trow) * 64 + off) =
                *(const short8*)(rp + trow * 136 + hh * 64 + off);
        }
    }
}

// ---------------- FFN1 GEMM: 128x128 tile, BK=32, 32KB LDS, 5 blocks/CU -------------
// The round-6-measured config (41.8 us, MfmaUtil 14.7%): wave 64x64, acc 4x4,
// two-phase gelu repack, grid 1024 = 4/CU even.
__global__ __launch_bounds__(256) void gemm_ffn1(const short* __restrict__ A,
                                                 const short* __restrict__ Bw,
                                                 const float* __restrict__ bias,
                                                 short* __restrict__ Cb,
                                                 int M, int N, int K)
{
    constexpr int BK = 32;
    constexpr int BUF = 128 * BK;               // 4096 shorts
    __shared__ short SMEM[4 * BUF];             // 32 KB; repack aliases (8704 <= 16384)
    short* Asb = SMEM;
    short* Bsb = SMEM + 2 * BUF;

    int tid = threadIdx.x;
    int w = tid >> 6, lane = tid & 63;
    int wr = w >> 1, wc = w & 1;                // wave tile 64m x 64n
    int nN = N >> 7;                            // 16
    int bid = blockIdx.x;
    int xcd = bid & 7, sq = bid >> 3;
    int mi = xcd + 8 * (sq / nN);
    int ni = sq % nN;
    int m0 = mi * 128, n0 = ni * 128;
    int quad = lane >> 4, l16 = lane & 15;

    f32x4 zero = {0.f, 0.f, 0.f, 0.f};
    f32x4 acc[4][4];
#pragma unroll
    for (int i = 0; i < 4; ++i)
#pragma unroll
        for (int j = 0; j < 4; ++j) acc[i][j] = zero;

    int rl = lane >> 2;                          // 0..15
    int ch = lane & 3;
    const short* Ag[2];
    const short* Bg[2];
    int ldsOff[2];
#pragma unroll
    for (int s = 0; s < 2; ++s) {
        int rowl = w * 32 + s * 16 + rl;
        int csw = (ch ^ ((rowl >> 1) & 3)) * 8;
        Ag[s] = A + (size_t)(m0 + rowl) * K + csw;
        Bg[s] = Bw + (size_t)(n0 + rowl) * K + csw;
        ldsOff[s] = (w * 32 + s * 16) * BK;
    }

    auto stage = [&](int kt, int pp) {
#pragma unroll
        for (int s = 0; s < 2; ++s) {
            async16(Ag[s] + kt, Asb + pp * BUF + ldsOff[s]);
            async16(Bg[s] + kt, Bsb + pp * BUF + ldsOff[s]);
        }
    };

    int aoff[4], boff[4];
#pragma unroll
    for (int i = 0; i < 4; ++i) {
        int ra = wr * 64 + i * 16 + l16;
        int rb = wc * 64 + i * 16 + l16;
        aoff[i] = ra * BK + (quad ^ ((ra >> 1) & 3)) * 8;
        boff[i] = rb * BK + (quad ^ ((rb >> 1) & 3)) * 8;
    }

    stage(0, 0);
    int p = 0;
    for (int kt = 0; kt < K; kt += BK) {
        __syncthreads();                        // buf[p] staged; prior reads done
        if (kt + BK < K) stage(kt + BK, p ^ 1); // prefetch overlaps MFMA
        short8 aF[4], bF[4];
#pragma unroll
        for (int i = 0; i < 4; ++i) {
            aF[i] = *(const short8*)(Asb + p * BUF + aoff[i]);
            bF[i] = *(const short8*)(Bsb + p * BUF + boff[i]);
        }
#pragma unroll
        for (int i = 0; i < 4; ++i)
#pragma unroll
            for (int j = 0; j < 4; ++j)
                acc[i][j] = __builtin_amdgcn_mfma_f32_16x16x32_bf16(
                    aF[i], bF[j], acc[i][j], 0, 0, 0);
        p ^= 1;
    }

    __syncthreads();                            // K-loop LDS dead -> repack
    short* rp = SMEM + w * 2176;                // 32 x 68 per phase
#pragma unroll
    for (int ph = 0; ph < 2; ++ph) {
#pragma unroll
        for (int i = 2 * ph; i < 2 * ph + 2; ++i) {
            int ml = (i - 2 * ph) * 16 + quad * 4;
#pragma unroll
            for (int j = 0; j < 4; ++j) {
                float bv = bias[n0 + wc * 64 + j * 16 + l16];
#pragma unroll
                for (int r = 0; r < 4; ++r)
                    rp[(ml + r) * 68 + j * 16 + l16] =
                        f2bf(gelu_fast(acc[i][j][r] + bv));
            }
        }
#pragma unroll
        for (int it = 0; it < 4; ++it) {
            int row = it * 8 + (lane >> 3);            // m local
            int off = (lane & 7) * 8;                  // n chunk
            *(short8*)(Cb + (size_t)(m0 + wr * 64 + 32 * ph + row) * N
                          + n0 + wc * 64 + off) =
                *(const short8*)(rp + row * 68 + off);
        }
    }
}

// ---------------- MFMA sliding-window attention ----------------
constexpr int QS = 72;    // Qs/Ks LDS row stride (shorts)
constexpr int VS = 200;   // Vt/Ps LDS row stride (shorts)

__global__ __launch_bounds__(256) void attn_mfma(const short* __restrict__ Qg,
                                                 const short* __restrict__ Kg,
                                                 const short* __restrict__ Vtg,
                                                 short* __restrict__ ctx)
{
    __shared__ short Qs[64 * QS];
    __shared__ short Ks[192 * QS];     // aliased as Ps[64*VS] later
    __shared__ short Vt[64 * VS];
    int tid = threadIdx.x;
    int w = tid >> 6, lane = tid & 63, quad = lane >> 4, l16 = lane & 15;
    int blk = blockIdx.x;
    int q0 = (blk & 31) << 6;
    int bh = blk >> 5;
    int kbase = q0 - 128;

    {
        const short* src = Qg + ((size_t)bh * 2048 + q0) * 64;
        for (int c = tid; c < 512; c += 256) {
            int row = c >> 3, off = (c & 7) * 8;
            *(short8*)(Qs + row * QS + off) = *(const short8*)(src + row * 64 + off);
        }
    }
    {
        const short* base = Kg + (size_t)bh * 2048 * 64;
        for (int c = tid; c < 1536; c += 256) {
            int row = c >> 3, off = (c & 7) * 8;
            int srow = kbase + row; srow = srow < 0 ? 0 : srow;
            *(short8*)(Ks + row * QS + off) = *(const short8*)(base + (size_t)srow * 64 + off);
        }
    }
    {
        const short* base = Vtg + (size_t)bh * 64 * 2048;
        for (int c = tid; c < 1536; c += 256) {
            int row = c / 24, cc = c - row * 24;
            int off = cc * 8;
            int scol = kbase + off; scol = scol < 0 ? 0 : scol;
            *(short8*)(Vt + row * VS + off) = *(const short8*)(base + (size_t)row * 2048 + scol);
        }
    }
    __syncthreads();

    short8 aF0 = *(const short8*)(Qs + (w * 16 + l16) * QS + quad * 8);
    short8 aF1 = *(const short8*)(Qs + (w * 16 + l16) * QS + 32 + quad * 8);
    f32x4 S[12];
    f32x4 zero = {0.f, 0.f, 0.f, 0.f};
#pragma unroll
    for (int t = 0; t < 12; ++t) S[t] = zero;
#pragma unroll
    for (int t = 0; t < 12; ++t) {
        short8 b0 = *(const short8*)(Ks + (t * 16 + l16) * QS + quad * 8);
        short8 b1 = *(const short8*)(Ks + (t * 16 + l16) * QS + 32 + quad * 8);
        S[t] = __builtin_amdgcn_mfma_f32_16x16x32_bf16(aF0, b0, S[t], 0, 0, 0);
        S[t] = __builtin_amdgcn_mfma_f32_16x16x32_bf16(aF1, b1, S[t], 0, 0, 0);
    }

    int i0 = w * 16 + quad * 4;
    float mrow[4] = {-INFINITY, -INFINITY, -INFINITY, -INFINITY};
#pragma unroll
    for (int t = 0; t < 12; ++t) {
        int jl = t * 16 + l16;
        int kg = kbase + jl;
#pragma unroll
        for (int r = 0; r < 4; ++r) {
            int dj = jl - (i0 + r);
            bool ok = (dj >= 1) && (dj <= 128) && (kg >= 0);
            float s = ok ? S[t][r] * 0.125f : -INFINITY;
            S[t][r] = s;
            mrow[r] = fmaxf(mrow[r], s);
        }
    }
#pragma unroll
    for (int off = 8; off >= 1; off >>= 1)
#pragma unroll
        for (int r = 0; r < 4; ++r)
            mrow[r] = fmaxf(mrow[r], __shfl_xor(mrow[r], off, 64));
    float sum[4] = {0.f, 0.f, 0.f, 0.f};
#pragma unroll
    for (int t = 0; t < 12; ++t)
#pragma unroll
        for (int r = 0; r < 4; ++r) {
            float p = __expf(S[t][r] - mrow[r]);
            S[t][r] = p;
            sum[r] += p;
        }
#pragma unroll
    for (int off = 8; off >= 1; off >>= 1)
#pragma unroll
        for (int r = 0; r < 4; ++r)
            sum[r] += __shfl_xor(sum[r], off, 64);
    float inv[4];
#pragma unroll
    for (int r = 0; r < 4; ++r) inv[r] = 1.0f / sum[r];

    __syncthreads();
    short* Ps = Ks;
#pragma unroll
    for (int t = 0; t < 12; ++t)
#pragma unroll
        for (int r = 0; r < 4; ++r)
            Ps[(w * 16 + quad * 4 + r) * VS + t * 16 + l16] = f2bf(S[t][r]);

    f32x4 O[4];
#pragma unroll
    for (int tN = 0; tN < 4; ++tN) O[tN] = zero;
#pragma unroll
    for (int s = 0; s < 6; ++s) {
        short8 aP = *(const short8*)(Ps + (w * 16 + l16) * VS + s * 32 + quad * 8);
#pragma unroll
        for (int tN = 0; tN < 4; ++tN) {
            short8 bV = *(const short8*)(Vt + (tN * 16 + l16) * VS + s * 32 + quad * 8);
            O[tN] = __builtin_amdgcn_mfma_f32_16x16x32_bf16(aP, bV, O[tN], 0, 0, 0);
        }
    }

    int b = bh >> 3, h = bh & 7;
#pragma unroll
    for (int tN = 0; tN < 4; ++tN)
#pragma unroll
        for (int r = 0; r < 4; ++r) {
            int trow = q0 + w * 16 + quad * 4 + r;
            ctx[((size_t)(b * 2048 + trow)) * 512 + h * 64 + tN * 16 + l16] =
                f2bf(O[tN][r] * inv[r]);
        }
}

extern "C" void kernel_launch(void* const* d_in, const int* in_sizes, int n_in,
                              void* d_out, int out_size, void* d_ws, size_t ws_size,
                              hipStream_t stream)
{
    const float* x         = (const float*)d_in[0];
    const float* in_proj_w = (const float*)d_in[1];
    const float* in_proj_b = (const float*)d_in[2];
    const float* out_w     = (const float*)d_in[3];
    const float* out_b     = (const float*)d_in[4];
    const float* ln1_g     = (const float*)d_in[5];
    const float* ln1_b     = (const float*)d_in[6];
    const float* ln2_g     = (const float*)d_in[7];
    const float* ln2_b     = (const float*)d_in[8];
    const float* w1        = (const float*)d_in[9];
    const float* b1        = (const float*)d_in[10];
    const float* w2        = (const float*)d_in[11];
    const float* b2        = (const float*)d_in[12];
    float* out = (float*)d_out;

    // ws layout:
    //   0-32 MB : attnQ/K/V (8 MB each) -> later hbuf (32 MB)
    //   32-40   : regB (x2 / ctx / x3 bf16)
    //   40-46.3 : bf16 weights
    //   48-56   : res1 (bf16 residual after attention)
    char* ws = (char*)d_ws;
    short* attnQ = (short*)ws;
    short* attnK = (short*)(ws + (size_t)8 * 1024 * 1024);
    short* attnV = (short*)(ws + (size_t)16 * 1024 * 1024);
    short* hbuf  = (short*)ws;
    short* regB  = (short*)(ws + (size_t)32 * 1024 * 1024);
    short* wq  = (short*)(ws + (size_t)40 * 1024 * 1024);
    short* wo  = wq + (size_t)QKVD * Dn;
    short* w1b = wo + (size_t)Dn * Dn;
    short* w2b = w1b + (size_t)Fn * Dn;
    short* res1 = (short*)(ws + (size_t)48 * 1024 * 1024);

    // 0+1) weight cvt + LN1 fused
    prep_kernel<<<5120, 256, 0, stream>>>(in_proj_w, out_w, w1, w2, wq, wo, w1b, w2b,
                                          x, ln1_g, ln1_b, regB);
    // 2) qkv = x2 @ in_proj_w^T + b -> bf16 attention layouts (64x256 tiles, 3/CU)
    gemm_qkv<<<(Mrows / 64) * (QKVD / 256), 256, 0, stream>>>(
        regB, wq, in_proj_b, attnQ, attnK, attnV, Mrows, QKVD, Dn);
    // 3) ctx = attention -> bf16 (B,T,512)
    attn_mfma<<<Bn * Hn * (Tn / 64), 256, 0, stream>>>(attnQ, attnK, attnV, regB);
    // 4) res1 = bf16(x + ctx @ out_w^T + out_b)
    gemm_res<0, 1><<<(Mrows / 64) * (Dn / 128), 256, 0, stream>>>(
        regB, wo, out_b, x, res1, Mrows, Dn, Dn);
    // 5) x3 = LN2(res1) -> bf16
    ln2_kernel<<<Mrows / 4, 256, 0, stream>>>(res1, ln2_g, ln2_b, regB);
    // 6) h = gelu(x3 @ w1^T + b1) -> bf16 (128x128 tiles, 5 blocks/CU, grid 1024)
    gemm_ffn1<<<(Mrows / 128) * (Fn / 128), 256, 0, stream>>>(
        regB, w1b, b1, hbuf, Mrows, Fn, Dn);
    // 7) out = res1 + h @ w2^T + b2 -> f32
    gemm_res<1, 0><<<(Mrows / 64) * (Dn / 128), 256, 0, stream>>>(
        hbuf, w2b, b2, res1, out, Mrows, Dn, Fn);
}

// Round 14
// 212.621 us; speedup vs baseline: 1.0157x; 1.0157x over previous
//
#include <hip/hip_runtime.h>
#include <math.h>

// Problem constants
constexpr int Bn = 4;
constexpr int Tn = 2048;
constexpr int Dn = 512;
constexpr int Hn = 8;
constexpr int HDn = 64;       // head dim
constexpr int Fn = 2048;
constexpr int WIN = 128;
constexpr float EPS = 1e-5f;
constexpr int Mrows = Bn * Tn;          // 8192
constexpr int QKVD = 3 * Dn;            // 1536

using short8 = __attribute__((ext_vector_type(8))) short;
using f32x4  = __attribute__((ext_vector_type(4))) float;

// fp32 -> bf16 (RNE) as raw short
__device__ __forceinline__ short f2bf(float f) {
    unsigned u = __float_as_uint(f);
    unsigned r = (u + 0x7FFFu + ((u >> 16) & 1u)) >> 16;
    return (short)r;
}
__device__ __forceinline__ float bf2f(short s) {
    return __uint_as_float(((unsigned)(unsigned short)s) << 16);
}

// tanh-form GELU (max abs dev from exact < 1e-3; threshold is 0.104)
__device__ __forceinline__ float gelu_fast(float v) {
    float u = 1.5957691216f * v * (1.0f + 0.044715f * v * v);
    float t = 1.0f - 2.0f / (__expf(u) + 1.0f);
    return 0.5f * v * (1.0f + t);
}

// async 16B global -> LDS (wave-uniform LDS base; HW scatters lane i at base+16*i;
// global address may vary arbitrarily per lane)
__device__ __forceinline__ void async16(const short* g, short* l) {
    __builtin_amdgcn_global_load_lds(
        (const __attribute__((address_space(1))) void*)g,
        (__attribute__((address_space(3))) void*)l,
        16, 0, 0);
}

// ---------------- LN body, f32 input (wave-local, one row of 512) ----------------
__device__ __forceinline__ void ln_row(const float* __restrict__ xrow,
                                       const float* __restrict__ g,
                                       const float* __restrict__ b,
                                       short* __restrict__ yrow, int lane)
{
    const float4* xr = (const float4*)xrow;
    float4 v0 = xr[lane];
    float4 v1 = xr[lane + 64];
    float s = v0.x + v0.y + v0.z + v0.w + v1.x + v1.y + v1.z + v1.w;
#pragma unroll
    for (int off = 32; off >= 1; off >>= 1) s += __shfl_xor(s, off, 64);
    float mu = s * (1.0f / Dn);
    float d0x = v0.x - mu, d0y = v0.y - mu, d0z = v0.z - mu, d0w = v0.w - mu;
    float d1x = v1.x - mu, d1y = v1.y - mu, d1z = v1.z - mu, d1w = v1.w - mu;
    float q = d0x*d0x + d0y*d0y + d0z*d0z + d0w*d0w
            + d1x*d1x + d1y*d1y + d1z*d1z + d1w*d1w;
#pragma unroll
    for (int off = 32; off >= 1; off >>= 1) q += __shfl_xor(q, off, 64);
    float inv = rsqrtf(q * (1.0f / Dn) + EPS);
    const float4* gr = (const float4*)g;
    const float4* br = (const float4*)b;
    float4 g0 = gr[lane], g1 = gr[lane + 64];
    float4 b0 = br[lane], b1 = br[lane + 64];
    short4 a0, a1;
    a0.x = f2bf(d0x * inv * g0.x + b0.x);
    a0.y = f2bf(d0y * inv * g0.y + b0.y);
    a0.z = f2bf(d0z * inv * g0.z + b0.z);
    a0.w = f2bf(d0w * inv * g0.w + b0.w);
    a1.x = f2bf(d1x * inv * g1.x + b1.x);
    a1.y = f2bf(d1y * inv * g1.y + b1.y);
    a1.z = f2bf(d1z * inv * g1.z + b1.z);
    a1.w = f2bf(d1w * inv * g1.w + b1.w);
    short4* yr = (short4*)yrow;
    yr[lane] = a0;
    yr[lane + 64] = a1;
}

// ---------------- prep: weight cvt (blocks 0..3071) + LN1 (blocks 3072..5119) -------
__global__ __launch_bounds__(256) void prep_kernel(const float* __restrict__ s0,
                                                   const float* __restrict__ s1,
                                                   const float* __restrict__ s2,
                                                   const float* __restrict__ s3,
                                                   short* __restrict__ d0,
                                                   short* __restrict__ d1,
                                                   short* __restrict__ d2,
                                                   short* __restrict__ d3,
                                                   const float* __restrict__ x,
                                                   const float* __restrict__ ln1_g,
                                                   const float* __restrict__ ln1_b,
                                                   short* __restrict__ x2)
{
    int bid = blockIdx.x;
    if (bid < 3072) {
        int i = bid * 256 + threadIdx.x;
        const float* src; short* dst; int j;
        if (i < 196608)      { src = s0; dst = d0; j = i; }
        else if (i < 262144) { src = s1; dst = d1; j = i - 196608; }
        else if (i < 524288) { src = s2; dst = d2; j = i - 262144; }
        else                 { src = s3; dst = d3; j = i - 524288; }
        float4 v = ((const float4*)src)[j];
        short4 o;
        o.x = f2bf(v.x); o.y = f2bf(v.y); o.z = f2bf(v.z); o.w = f2bf(v.w);
        ((short4*)dst)[j] = o;
    } else {
        int row = (bid - 3072) * 4 + (threadIdx.x >> 6);
        int lane = threadIdx.x & 63;
        ln_row(x + (size_t)row * Dn, ln1_g, ln1_b, x2 + (size_t)row * Dn, lane);
    }
}

// ---------------- LN2: bf16 input (res1), bf16 output; one wave per row -------------
__global__ __launch_bounds__(256) void ln2_kernel(const short* __restrict__ xh,
                                                  const float* __restrict__ g,
                                                  const float* __restrict__ b,
                                                  short* __restrict__ y)
{
    int row = blockIdx.x * 4 + (threadIdx.x >> 6);
    int lane = threadIdx.x & 63;
    const short* xrow = xh + (size_t)row * Dn;
    short8 v = *(const short8*)(xrow + lane * 8);
    float f[8];
#pragma unroll
    for (int k = 0; k < 8; ++k) f[k] = bf2f(v[k]);
    float s = 0.f;
#pragma unroll
    for (int k = 0; k < 8; ++k) s += f[k];
#pragma unroll
    for (int off = 32; off >= 1; off >>= 1) s += __shfl_xor(s, off, 64);
    float mu = s * (1.0f / Dn);
    float q = 0.f;
#pragma unroll
    for (int k = 0; k < 8; ++k) { float d = f[k] - mu; q += d * d; }
#pragma unroll
    for (int off = 32; off >= 1; off >>= 1) q += __shfl_xor(q, off, 64);
    float inv = rsqrtf(q * (1.0f / Dn) + EPS);
    const float4* gr = (const float4*)g;
    const float4* br = (const float4*)b;
    float4 g0 = gr[2 * lane], g1 = gr[2 * lane + 1];
    float4 b0 = br[2 * lane], b1 = br[2 * lane + 1];
    float gg[8] = {g0.x, g0.y, g0.z, g0.w, g1.x, g1.y, g1.z, g1.w};
    float bb[8] = {b0.x, b0.y, b0.z, b0.w, b1.x, b1.y, b1.z, b1.w};
    short8 o;
#pragma unroll
    for (int k = 0; k < 8; ++k) o[k] = f2bf((f[k] - mu) * inv * gg[k] + bb[k]);
    *(short8*)(y + (size_t)row * Dn + lane * 8) = o;
}

// ------- gemm_res: 64x128 tile, BK=64, double-buffered, 2 blocks/CU ----
// RIN: 0 = resid f32, 1 = resid bf16. OUT: 0 = f32 direct, 1 = bf16 via LDS repack.
template <int RIN, int OUT>
__global__ __launch_bounds__(256) void gemm_res(const short* __restrict__ A,
                                                const short* __restrict__ Bw,
                                                const float* __restrict__ bias,
                                                const void* __restrict__ resid,
                                                void* __restrict__ Cout,
                                                int M, int N, int K)
{
    constexpr int BK = 64;
    constexpr int ABUF = 64 * BK;               // 4096 shorts
    constexpr int BBUF = 128 * BK;              // 8192 shorts
    __shared__ short SMEM[2 * (ABUF + BBUF)];   // 48 KB
    short* Asb = SMEM;
    short* Bsb = SMEM + 2 * ABUF;

    int tid = threadIdx.x;
    int w = tid >> 6, lane = tid & 63;
    int wr = w >> 1, wc = w & 1;                // wave tile 32m x 64n
    int nN = N >> 7;
    int bid = blockIdx.x;
    int xcd = bid & 7, sq = bid >> 3;
    int mi = xcd + 8 * (sq / nN);
    int ni = sq % nN;
    int m0 = mi * 64, n0 = ni * 128;
    int quad = lane >> 4, l16 = lane & 15;

    f32x4 zero = {0.f, 0.f, 0.f, 0.f};
    f32x4 acc[2][4];
#pragma unroll
    for (int i = 0; i < 2; ++i)
#pragma unroll
        for (int j = 0; j < 4; ++j) acc[i][j] = zero;

    int rl = lane >> 3;                          // 0..7
    int ch = lane & 7;
    const short* Ag[2];
    const short* Bg[4];
    int aOff[2], bOff[4];
#pragma unroll
    for (int s = 0; s < 2; ++s) {
        int rowl = w * 16 + s * 8 + rl;
        int csw = (ch ^ (rowl & 7)) * 8;
        Ag[s] = A + (size_t)(m0 + rowl) * K + csw;
        aOff[s] = (w * 16 + s * 8) * BK;
    }
#pragma unroll
    for (int s = 0; s < 4; ++s) {
        int rowl = w * 32 + s * 8 + rl;
        int csw = (ch ^ (rowl & 7)) * 8;
        Bg[s] = Bw + (size_t)(n0 + rowl) * K + csw;
        bOff[s] = (w * 32 + s * 8) * BK;
    }

    auto stage = [&](int kt, int pp) {
#pragma unroll
        for (int s = 0; s < 2; ++s)
            async16(Ag[s] + kt, Asb + pp * ABUF + aOff[s]);
#pragma unroll
        for (int s = 0; s < 4; ++s)
            async16(Bg[s] + kt, Bsb + pp * BBUF + bOff[s]);
    };

    stage(0, 0);
    int p = 0;
    for (int kt = 0; kt < K; kt += BK) {
        __syncthreads();
        if (kt + BK < K) stage(kt + BK, p ^ 1);
        short8 aF[2][2], bF[2][4];
#pragma unroll
        for (int kk = 0; kk < 2; ++kk) {
#pragma unroll
            for (int i = 0; i < 2; ++i) {
                int ra = wr * 32 + i * 16 + l16;
                int cs = ((kk * 4 + quad) ^ (ra & 7)) * 8;
                aF[kk][i] = *(const short8*)(Asb + p * ABUF + ra * BK + cs);
            }
#pragma unroll
            for (int j = 0; j < 4; ++j) {
                int rb = wc * 64 + j * 16 + l16;
                int cs = ((kk * 4 + quad) ^ (rb & 7)) * 8;
                bF[kk][j] = *(const short8*)(Bsb + p * BBUF + rb * BK + cs);
            }
        }
#pragma unroll
        for (int kk = 0; kk < 2; ++kk)
#pragma unroll
            for (int i = 0; i < 2; ++i)
#pragma unroll
                for (int j = 0; j < 4; ++j)
                    acc[i][j] = __builtin_amdgcn_mfma_f32_16x16x32_bf16(
                        aF[kk][i], bF[kk][j], acc[i][j], 0, 0, 0);
        p ^= 1;
    }

    const float* rf = (const float*)resid;
    const short* rh = (const short*)resid;

    if constexpr (OUT == 0) {
        float* Cf = (float*)Cout;
#pragma unroll
        for (int j = 0; j < 4; ++j) {
            int n = n0 + wc * 64 + j * 16 + l16;
            float bv = bias[n];
#pragma unroll
            for (int i = 0; i < 2; ++i) {
                int mbase = m0 + wr * 32 + i * 16 + quad * 4;
#pragma unroll
                for (int r = 0; r < 4; ++r) {
                    size_t idx = (size_t)(mbase + r) * N + n;
                    float rv = RIN ? bf2f(rh[idx]) : rf[idx];
                    Cf[idx] = acc[i][j][r] + bv + rv;
                }
            }
        }
    } else {
        // bf16 out via LDS repack (full-line short8 stores)
        __syncthreads();
        short* rp = SMEM + w * 6144;             // 32 x 72 needed = 2304
#pragma unroll
        for (int j = 0; j < 4; ++j) {
            int n = n0 + wc * 64 + j * 16 + l16;
            float bv = bias[n];
#pragma unroll
            for (int i = 0; i < 2; ++i) {
                int ml = i * 16 + quad * 4;
#pragma unroll
                for (int r = 0; r < 4; ++r) {
                    size_t idx = (size_t)(m0 + wr * 32 + ml + r) * N + n;
                    float rv = RIN ? bf2f(rh[idx]) : rf[idx];
                    rp[(ml + r) * 72 + j * 16 + l16] = f2bf(acc[i][j][r] + bv + rv);
                }
            }
        }
        short* Cb = (short*)Cout;
#pragma unroll
        for (int it = 0; it < 4; ++it) {
            int row = it * 8 + (lane >> 3);
            int off = (lane & 7) * 8;
            *(short8*)(Cb + (size_t)(m0 + wr * 32 + row) * N + n0 + wc * 64 + off) =
                *(const short8*)(rp + row * 72 + off);
        }
    }
}

// ---------------- QKV GEMM: 64x256 tile, BK=32, wave 32x128; grid 768 = 3/CU --------
__global__ __launch_bounds__(256, 3) void gemm_qkv(const short* __restrict__ A,
                                                   const short* __restrict__ Bw,
                                                   const float* __restrict__ bias,
                                                   short* __restrict__ q_out,
                                                   short* __restrict__ k_out,
                                                   short* __restrict__ v_out,
                                                   int M, int N, int K)
{
    constexpr int BK = 32;
    constexpr int ABUF = 64 * BK;               // 2048 shorts
    constexpr int BBUF = 256 * BK;              // 8192 shorts
    __shared__ short SMEM[2 * (ABUF + BBUF)];   // 20480 shorts = 40 KB
    short* Asb = SMEM;
    short* Bsb = SMEM + 2 * ABUF;

    int tid = threadIdx.x;
    int w = tid >> 6, lane = tid & 63;
    int wr = w >> 1, wc = w & 1;                // wave tile 32m x 128n
    int nT = N >> 8;                            // 6
    int bid = blockIdx.x;
    int xcd = bid & 7, sq = bid >> 3;
    int mi = xcd + 8 * (sq / nT);
    int ni = sq % nT;
    int m0 = mi * 64, n0 = ni * 256;
    int quad = lane >> 4, l16 = lane & 15;

    f32x4 zero = {0.f, 0.f, 0.f, 0.f};
    f32x4 acc[2][8];
#pragma unroll
    for (int i = 0; i < 2; ++i)
#pragma unroll
        for (int j = 0; j < 8; ++j) acc[i][j] = zero;

    int rl = lane >> 2;                          // 0..15
    int ch = lane & 3;
    const short* Ag;
    const short* Bg[4];
    int aOff, bOff[4];
    {
        int rowl = w * 16 + rl;
        int csw = (ch ^ ((rowl >> 1) & 3)) * 8;
        Ag = A + (size_t)(m0 + rowl) * K + csw;
        aOff = (w * 16) * BK;
    }
#pragma unroll
    for (int s = 0; s < 4; ++s) {
        int rowl = w * 64 + s * 16 + rl;
        int csw = (ch ^ ((rowl >> 1) & 3)) * 8;
        Bg[s] = Bw + (size_t)(n0 + rowl) * K + csw;
        bOff[s] = (w * 64 + s * 16) * BK;
    }

    auto stage = [&](int kt, int pp) {
        async16(Ag + kt, Asb + pp * ABUF + aOff);
#pragma unroll
        for (int s = 0; s < 4; ++s)
            async16(Bg[s] + kt, Bsb + pp * BBUF + bOff[s]);
    };

    int aoff[2], boff[8];
#pragma unroll
    for (int i = 0; i < 2; ++i) {
        int ra = wr * 32 + i * 16 + l16;
        aoff[i] = ra * BK + (quad ^ ((ra >> 1) & 3)) * 8;
    }
#pragma unroll
    for (int j = 0; j < 8; ++j) {
        int rb = wc * 128 + j * 16 + l16;
        boff[j] = rb * BK + (quad ^ ((rb >> 1) & 3)) * 8;
    }

    stage(0, 0);
    int p = 0;
    for (int kt = 0; kt < K; kt += BK) {
        __syncthreads();
        if (kt + BK < K) stage(kt + BK, p ^ 1);
        short8 aF[2], bF[8];
#pragma unroll
        for (int i = 0; i < 2; ++i)
            aF[i] = *(const short8*)(Asb + p * ABUF + aoff[i]);
#pragma unroll
        for (int j = 0; j < 8; ++j)
            bF[j] = *(const short8*)(Bsb + p * BBUF + boff[j]);
#pragma unroll
        for (int i = 0; i < 2; ++i)
#pragma unroll
            for (int j = 0; j < 8; ++j)
                acc[i][j] = __builtin_amdgcn_mfma_f32_16x16x32_bf16(
                    aF[i], bF[j], acc[i][j], 0, 0, 0);
        p ^= 1;
    }

    __syncthreads();                             // K-loop LDS dead -> repack
    short* rp = SMEM + w * 5120;                 // per-wave slot (5120 shorts)
    float bv[8];
#pragma unroll
    for (int j = 0; j < 8; ++j) bv[j] = bias[n0 + wc * 128 + j * 16 + l16];

    int b = m0 >> 11;
    int ncol0 = n0 + wc * 128;
    int sec = ncol0 >> 9;                        // 0=q 1=k 2=v (128-slice never crosses)
    int h0 = (ncol0 & 511) >> 6;                 // heads h0, h0+1
    int t0 = (m0 & 2047) + wr * 32;

    if (sec == 2) {
#pragma unroll
        for (int ph = 0; ph < 2; ++ph) {
#pragma unroll
            for (int j = 4 * ph; j < 4 * ph + 4; ++j) {
                int d = (j - 4 * ph) * 16 + l16;
#pragma unroll
                for (int i = 0; i < 2; ++i)
#pragma unroll
                    for (int r = 0; r < 4; ++r)
                        rp[d * 40 + i * 16 + quad * 4 + r] = f2bf(acc[i][j][r] + bv[j]);
            }
            int bh = b * 8 + h0 + ph;
#pragma unroll
            for (int it = 0; it < 4; ++it) {
                int drow = it * 16 + (lane >> 2);        // 0..63
                int toff = (lane & 3) * 8;               // 0..24
                *(short8*)(v_out + ((size_t)bh * 64 + drow) * 2048 + t0 + toff) =
                    *(const short8*)(rp + drow * 40 + toff);
            }
        }
    } else {
        short* dst = (sec == 0 ? q_out : k_out);
#pragma unroll
        for (int i = 0; i < 2; ++i) {
            int tl = i * 16 + quad * 4;
#pragma unroll
            for (int j = 0; j < 8; ++j)
#pragma unroll
                for (int r = 0; r < 4; ++r)
                    rp[(tl + r) * 136 + j * 16 + l16] = f2bf(acc[i][j][r] + bv[j]);
        }
#pragma unroll
        for (int it = 0; it < 8; ++it) {
            int trow = it * 4 + (lane >> 4);             // 0..31
            int hh = (lane & 15) >> 3;                   // head select
            int off = (lane & 7) * 8;                    // d chunk
            int bh = b * 8 + h0 + hh;
            *(short8*)(dst + ((size_t)bh * 2048 + t0 + trow) * 64 + off) =
                *(const short8*)(rp + trow * 136 + hh * 64 + off);
        }
    }
}

// ---------------- FFN1 GEMM: 128x128 tile, BK=32, 32KB LDS, grid 1024 ---------------
__global__ __launch_bounds__(256) void gemm_ffn1(const short* __restrict__ A,
                                                 const short* __restrict__ Bw,
                                                 const float* __restrict__ bias,
                                                 short* __restrict__ Cb,
                                                 int M, int N, int K)
{
    constexpr int BK = 32;
    constexpr int BUF = 128 * BK;               // 4096 shorts
    __shared__ short SMEM[4 * BUF];             // 32 KB; repack aliases
    short* Asb = SMEM;
    short* Bsb = SMEM + 2 * BUF;

    int tid = threadIdx.x;
    int w = tid >> 6, lane = tid & 63;
    int wr = w >> 1, wc = w & 1;                // wave tile 64m x 64n
    int nN = N >> 7;                            // 16
    int bid = blockIdx.x;
    int xcd = bid & 7, sq = bid >> 3;
    int mi = xcd + 8 * (sq / nN);
    int ni = sq % nN;
    int m0 = mi * 128, n0 = ni * 128;
    int quad = lane >> 4, l16 = lane & 15;

    f32x4 zero = {0.f, 0.f, 0.f, 0.f};
    f32x4 acc[4][4];
#pragma unroll
    for (int i = 0; i < 4; ++i)
#pragma unroll
        for (int j = 0; j < 4; ++j) acc[i][j] = zero;

    int rl = lane >> 2;                          // 0..15
    int ch = lane & 3;
    const short* Ag[2];
    const short* Bg[2];
    int ldsOff[2];
#pragma unroll
    for (int s = 0; s < 2; ++s) {
        int rowl = w * 32 + s * 16 + rl;
        int csw = (ch ^ ((rowl >> 1) & 3)) * 8;
        Ag[s] = A + (size_t)(m0 + rowl) * K + csw;
        Bg[s] = Bw + (size_t)(n0 + rowl) * K + csw;
        ldsOff[s] = (w * 32 + s * 16) * BK;
    }

    auto stage = [&](int kt, int pp) {
#pragma unroll
        for (int s = 0; s < 2; ++s) {
            async16(Ag[s] + kt, Asb + pp * BUF + ldsOff[s]);
            async16(Bg[s] + kt, Bsb + pp * BUF + ldsOff[s]);
        }
    };

    int aoff[4], boff[4];
#pragma unroll
    for (int i = 0; i < 4; ++i) {
        int ra = wr * 64 + i * 16 + l16;
        int rb = wc * 64 + i * 16 + l16;
        aoff[i] = ra * BK + (quad ^ ((ra >> 1) & 3)) * 8;
        boff[i] = rb * BK + (quad ^ ((rb >> 1) & 3)) * 8;
    }

    stage(0, 0);
    int p = 0;
    for (int kt = 0; kt < K; kt += BK) {
        __syncthreads();
        if (kt + BK < K) stage(kt + BK, p ^ 1);
        short8 aF[4], bF[4];
#pragma unroll
        for (int i = 0; i < 4; ++i) {
            aF[i] = *(const short8*)(Asb + p * BUF + aoff[i]);
            bF[i] = *(const short8*)(Bsb + p * BUF + boff[i]);
        }
#pragma unroll
        for (int i = 0; i < 4; ++i)
#pragma unroll
            for (int j = 0; j < 4; ++j)
                acc[i][j] = __builtin_amdgcn_mfma_f32_16x16x32_bf16(
                    aF[i], bF[j], acc[i][j], 0, 0, 0);
        p ^= 1;
    }

    __syncthreads();                            // K-loop LDS dead -> repack
    short* rp = SMEM + w * 2176;                // 32 x 68 per phase
#pragma unroll
    for (int ph = 0; ph < 2; ++ph) {
#pragma unroll
        for (int i = 2 * ph; i < 2 * ph + 2; ++i) {
            int ml = (i - 2 * ph) * 16 + quad * 4;
#pragma unroll
            for (int j = 0; j < 4; ++j) {
                float bv = bias[n0 + wc * 64 + j * 16 + l16];
#pragma unroll
                for (int r = 0; r < 4; ++r)
                    rp[(ml + r) * 68 + j * 16 + l16] =
                        f2bf(gelu_fast(acc[i][j][r] + bv));
            }
        }
#pragma unroll
        for (int it = 0; it < 4; ++it) {
            int row = it * 8 + (lane >> 3);            // m local
            int off = (lane & 7) * 8;                  // n chunk
            *(short8*)(Cb + (size_t)(m0 + wr * 64 + 32 * ph + row) * N
                          + n0 + wc * 64 + off) =
                *(const short8*)(rp + row * 68 + off);
        }
    }
}

// ---------------- MFMA sliding-window attention (async-staged Q/K) ----------------
// One block: one (b,h), 64-query tile. Keys [q0-128, q0+64) = 192.
// Qg/Kg: [bh][t][64] bf16; Vtg: [bh][64][2048] bf16 (dim-major). ctx: (B,T,512) bf16.
// Q/K staged via global_load_lds (per-lane global gather, wave-uniform LDS base),
// unpadded 64-short rows with chunk XOR swizzle (c ^= row&7) -> <=2-way banks.
constexpr int VS = 200;   // Vt/Ps LDS row stride (shorts)

__global__ __launch_bounds__(256) void attn_mfma(const short* __restrict__ Qg,
                                                 const short* __restrict__ Kg,
                                                 const short* __restrict__ Vtg,
                                                 short* __restrict__ ctx)
{
    // LDS layout (shorts):
    //   [0, 4096)      Qs 64x64 swizzled   } dead after S-loop
    //   [4096, 16384)  Ks 192x64 swizzled  } dead after S-loop
    //   [0, 12800)     Ps 64xVS (aliases Qs/Ks after barrier)
    //   [16384, 29184) Vt 64xVS (register-staged, padded)
    __shared__ short SM[29184];
    short* Qs = SM;
    short* Ks = SM + 4096;
    short* Vt = SM + 16384;
    short* Ps = SM;

    int tid = threadIdx.x;
    int w = tid >> 6, lane = tid & 63, quad = lane >> 4, l16 = lane & 15;
    int blk = blockIdx.x;
    int q0 = (blk & 31) << 6;
    int bh = blk >> 5;
    int kbase = q0 - 128;

    // async stage Q (8 instrs: 2/wave, 8 rows each) and K (24 instrs: 6/wave)
    {
        int r8 = lane >> 3, lc = lane & 7;
        const short* qb = Qg + ((size_t)bh * 2048 + q0) * 64;
#pragma unroll
        for (int s = 0; s < 2; ++s) {
            int rowbase = w * 16 + s * 8;
            int row = rowbase + r8;
            int gc = lc ^ (row & 7);
            async16(qb + (size_t)row * 64 + gc * 8, Qs + rowbase * 64);
        }
        const short* kb = Kg + (size_t)bh * 2048 * 64;
#pragma unroll
        for (int s = 0; s < 6; ++s) {
            int rowbase = w * 48 + s * 8;
            int row = rowbase + r8;
            int gc = lc ^ (row & 7);
            int srow = kbase + row; srow = srow < 0 ? 0 : srow;
            async16(kb + (size_t)srow * 64 + gc * 8, Ks + rowbase * 64);
        }
    }
    // register-stage Vt (non-pow2 chunk count; padded stride)
    {
        const short* base = Vtg + (size_t)bh * 64 * 2048;
        for (int c = tid; c < 1536; c += 256) {
            int row = c / 24, cc = c - row * 24;
            int off = cc * 8;
            int scol = kbase + off; scol = scol < 0 ? 0 : scol;
            *(short8*)(Vt + row * VS + off) = *(const short8*)(base + (size_t)row * 2048 + scol);
        }
    }
    __syncthreads();   // drains vmcnt (async Q/K) + lgkmcnt (V ds_writes)

    int qrow = w * 16 + l16;
    short8 aF0 = *(const short8*)(Qs + qrow * 64 + ((quad ^ (qrow & 7)) * 8));
    short8 aF1 = *(const short8*)(Qs + qrow * 64 + (((4 + quad) ^ (qrow & 7)) * 8));
    f32x4 S[12];
    f32x4 zero = {0.f, 0.f, 0.f, 0.f};
#pragma unroll
    for (int t = 0; t < 12; ++t) S[t] = zero;
#pragma unroll
    for (int t = 0; t < 12; ++t) {
        int krow = t * 16 + l16;
        short8 b0 = *(const short8*)(Ks + krow * 64 + ((quad ^ (krow & 7)) * 8));
        short8 b1 = *(const short8*)(Ks + krow * 64 + (((4 + quad) ^ (krow & 7)) * 8));
        S[t] = __builtin_amdgcn_mfma_f32_16x16x32_bf16(aF0, b0, S[t], 0, 0, 0);
        S[t] = __builtin_amdgcn_mfma_f32_16x16x32_bf16(aF1, b1, S[t], 0, 0, 0);
    }

    int i0 = w * 16 + quad * 4;
    float mrow[4] = {-INFINITY, -INFINITY, -INFINITY, -INFINITY};
#pragma unroll
    for (int t = 0; t < 12; ++t) {
        int jl = t * 16 + l16;
        int kg = kbase + jl;
#pragma unroll
        for (int r = 0; r < 4; ++r) {
            int dj = jl - (i0 + r);
            bool ok = (dj >= 1) && (dj <= 128) && (kg >= 0);
            float s = ok ? S[t][r] * 0.125f : -INFINITY;
            S[t][r] = s;
            mrow[r] = fmaxf(mrow[r], s);
        }
    }
#pragma unroll
    for (int off = 8; off >= 1; off >>= 1)
#pragma unroll
        for (int r = 0; r < 4; ++r)
            mrow[r] = fmaxf(mrow[r], __shfl_xor(mrow[r], off, 64));
    float sum[4] = {0.f, 0.f, 0.f, 0.f};
#pragma unroll
    for (int t = 0; t < 12; ++t)
#pragma unroll
        for (int r = 0; r < 4; ++r) {
            float p = __expf(S[t][r] - mrow[r]);
            S[t][r] = p;
            sum[r] += p;
        }
#pragma unroll
    for (int off = 8; off >= 1; off >>= 1)
#pragma unroll
        for (int r = 0; r < 4; ++r)
            sum[r] += __shfl_xor(sum[r], off, 64);
    float inv[4];
#pragma unroll
    for (int r = 0; r < 4; ++r) inv[r] = 1.0f / sum[r];

    __syncthreads();   // all waves done reading Qs/Ks -> alias as Ps
#pragma unroll
    for (int t = 0; t < 12; ++t)
#pragma unroll
        for (int r = 0; r < 4; ++r)
            Ps[(w * 16 + quad * 4 + r) * VS + t * 16 + l16] = f2bf(S[t][r]);
    // same-wave write->read: compiler inserts lgkmcnt wait; no barrier needed

    f32x4 O[4];
#pragma unroll
    for (int tN = 0; tN < 4; ++tN) O[tN] = zero;
#pragma unroll
    for (int s = 0; s < 6; ++s) {
        short8 aP = *(const short8*)(Ps + (w * 16 + l16) * VS + s * 32 + quad * 8);
#pragma unroll
        for (int tN = 0; tN < 4; ++tN) {
            short8 bV = *(const short8*)(Vt + (tN * 16 + l16) * VS + s * 32 + quad * 8);
            O[tN] = __builtin_amdgcn_mfma_f32_16x16x32_bf16(aP, bV, O[tN], 0, 0, 0);
        }
    }

    int b = bh >> 3, h = bh & 7;
#pragma unroll
    for (int tN = 0; tN < 4; ++tN)
#pragma unroll
        for (int r = 0; r < 4; ++r) {
            int trow = q0 + w * 16 + quad * 4 + r;
            ctx[((size_t)(b * 2048 + trow)) * 512 + h * 64 + tN * 16 + l16] =
                f2bf(O[tN][r] * inv[r]);
        }
}

extern "C" void kernel_launch(void* const* d_in, const int* in_sizes, int n_in,
                              void* d_out, int out_size, void* d_ws, size_t ws_size,
                              hipStream_t stream)
{
    const float* x         = (const float*)d_in[0];
    const float* in_proj_w = (const float*)d_in[1];
    const float* in_proj_b = (const float*)d_in[2];
    const float* out_w     = (const float*)d_in[3];
    const float* out_b     = (const float*)d_in[4];
    const float* ln1_g     = (const float*)d_in[5];
    const float* ln1_b     = (const float*)d_in[6];
    const float* ln2_g     = (const float*)d_in[7];
    const float* ln2_b     = (const float*)d_in[8];
    const float* w1        = (const float*)d_in[9];
    const float* b1        = (const float*)d_in[10];
    const float* w2        = (const float*)d_in[11];
    const float* b2        = (const float*)d_in[12];
    float* out = (float*)d_out;

    // ws layout:
    //   0-32 MB : attnQ/K/V (8 MB each) -> later hbuf (32 MB)
    //   32-40   : regB (x2 / ctx / x3 bf16)
    //   40-46.3 : bf16 weights
    //   48-56   : res1 (bf16 residual after attention)
    char* ws = (char*)d_ws;
    short* attnQ = (short*)ws;
    short* attnK = (short*)(ws + (size_t)8 * 1024 * 1024);
    short* attnV = (short*)(ws + (size_t)16 * 1024 * 1024);
    short* hbuf  = (short*)ws;
    short* regB  = (short*)(ws + (size_t)32 * 1024 * 1024);
    short* wq  = (short*)(ws + (size_t)40 * 1024 * 1024);
    short* wo  = wq + (size_t)QKVD * Dn;
    short* w1b = wo + (size_t)Dn * Dn;
    short* w2b = w1b + (size_t)Fn * Dn;
    short* res1 = (short*)(ws + (size_t)48 * 1024 * 1024);

    // 0+1) weight cvt + LN1 fused
    prep_kernel<<<5120, 256, 0, stream>>>(in_proj_w, out_w, w1, w2, wq, wo, w1b, w2b,
                                          x, ln1_g, ln1_b, regB);
    // 2) qkv = x2 @ in_proj_w^T + b -> bf16 attention layouts (64x256 tiles, 3/CU)
    gemm_qkv<<<(Mrows / 64) * (QKVD / 256), 256, 0, stream>>>(
        regB, wq, in_proj_b, attnQ, attnK, attnV, Mrows, QKVD, Dn);
    // 3) ctx = attention -> bf16 (B,T,512)
    attn_mfma<<<Bn * Hn * (Tn / 64), 256, 0, stream>>>(attnQ, attnK, attnV, regB);
    // 4) res1 = bf16(x + ctx @ out_w^T + out_b)
    gemm_res<0, 1><<<(Mrows / 64) * (Dn / 128), 256, 0, stream>>>(
        regB, wo, out_b, x, res1, Mrows, Dn, Dn);
    // 5) x3 = LN2(res1) -> bf16
    ln2_kernel<<<Mrows / 4, 256, 0, stream>>>(res1, ln2_g, ln2_b, regB);
    // 6) h = gelu(x3 @ w1^T + b1) -> bf16 (128x128 tiles, grid 1024)
    gemm_ffn1<<<(Mrows / 128) * (Fn / 128), 256, 0, stream>>>(
        regB, w1b, b1, hbuf, Mrows, Fn, Dn);
    // 7) out = res1 + h @ w2^T + b2 -> f32
    gemm_res<1, 0><<<(Mrows / 64) * (Dn / 128), 256, 0, stream>>>(
        hbuf, w2b, b2, res1, out, Mrows, Dn, Fn);
}

// Round 15
// 208.788 us; speedup vs baseline: 1.0344x; 1.0184x over previous
//
#include <hip/hip_runtime.h>
#include <math.h>

// Problem constants
constexpr int Bn = 4;
constexpr int Tn = 2048;
constexpr int Dn = 512;
constexpr int Hn = 8;
constexpr int HDn = 64;       // head dim
constexpr int Fn = 2048;
constexpr int WIN = 128;
constexpr float EPS = 1e-5f;
constexpr int Mrows = Bn * Tn;          // 8192
constexpr int QKVD = 3 * Dn;            // 1536

using short8 = __attribute__((ext_vector_type(8))) short;
using f32x4  = __attribute__((ext_vector_type(4))) float;

// fp32 -> bf16 (RNE) as raw short
__device__ __forceinline__ short f2bf(float f) {
    unsigned u = __float_as_uint(f);
    unsigned r = (u + 0x7FFFu + ((u >> 16) & 1u)) >> 16;
    return (short)r;
}
__device__ __forceinline__ float bf2f(short s) {
    return __uint_as_float(((unsigned)(unsigned short)s) << 16);
}

// tanh-form GELU (max abs dev from exact < 1e-3; threshold is 0.104)
__device__ __forceinline__ float gelu_fast(float v) {
    float u = 1.5957691216f * v * (1.0f + 0.044715f * v * v);
    float t = 1.0f - 2.0f / (__expf(u) + 1.0f);
    return 0.5f * v * (1.0f + t);
}

// async 16B global -> LDS (wave-uniform LDS base; HW scatters lane i at base+16*i;
// global address may vary arbitrarily per lane)
__device__ __forceinline__ void async16(const short* g, short* l) {
    __builtin_amdgcn_global_load_lds(
        (const __attribute__((address_space(1))) void*)g,
        (__attribute__((address_space(3))) void*)l,
        16, 0, 0);
}

// ---------------- LN body, f32 input (wave-local, one row of 512) ----------------
__device__ __forceinline__ void ln_row(const float* __restrict__ xrow,
                                       const float* __restrict__ g,
                                       const float* __restrict__ b,
                                       short* __restrict__ yrow, int lane)
{
    const float4* xr = (const float4*)xrow;
    float4 v0 = xr[lane];
    float4 v1 = xr[lane + 64];
    float s = v0.x + v0.y + v0.z + v0.w + v1.x + v1.y + v1.z + v1.w;
#pragma unroll
    for (int off = 32; off >= 1; off >>= 1) s += __shfl_xor(s, off, 64);
    float mu = s * (1.0f / Dn);
    float d0x = v0.x - mu, d0y = v0.y - mu, d0z = v0.z - mu, d0w = v0.w - mu;
    float d1x = v1.x - mu, d1y = v1.y - mu, d1z = v1.z - mu, d1w = v1.w - mu;
    float q = d0x*d0x + d0y*d0y + d0z*d0z + d0w*d0w
            + d1x*d1x + d1y*d1y + d1z*d1z + d1w*d1w;
#pragma unroll
    for (int off = 32; off >= 1; off >>= 1) q += __shfl_xor(q, off, 64);
    float inv = rsqrtf(q * (1.0f / Dn) + EPS);
    const float4* gr = (const float4*)g;
    const float4* br = (const float4*)b;
    float4 g0 = gr[lane], g1 = gr[lane + 64];
    float4 b0 = br[lane], b1 = br[lane + 64];
    short4 a0, a1;
    a0.x = f2bf(d0x * inv * g0.x + b0.x);
    a0.y = f2bf(d0y * inv * g0.y + b0.y);
    a0.z = f2bf(d0z * inv * g0.z + b0.z);
    a0.w = f2bf(d0w * inv * g0.w + b0.w);
    a1.x = f2bf(d1x * inv * g1.x + b1.x);
    a1.y = f2bf(d1y * inv * g1.y + b1.y);
    a1.z = f2bf(d1z * inv * g1.z + b1.z);
    a1.w = f2bf(d1w * inv * g1.w + b1.w);
    short4* yr = (short4*)yrow;
    yr[lane] = a0;
    yr[lane + 64] = a1;
}

// ---------------- prep: weight cvt (blocks 0..3071) + LN1 (blocks 3072..5119) -------
__global__ __launch_bounds__(256) void prep_kernel(const float* __restrict__ s0,
                                                   const float* __restrict__ s1,
                                                   const float* __restrict__ s2,
                                                   const float* __restrict__ s3,
                                                   short* __restrict__ d0,
                                                   short* __restrict__ d1,
                                                   short* __restrict__ d2,
                                                   short* __restrict__ d3,
                                                   const float* __restrict__ x,
                                                   const float* __restrict__ ln1_g,
                                                   const float* __restrict__ ln1_b,
                                                   short* __restrict__ x2)
{
    int bid = blockIdx.x;
    if (bid < 3072) {
        int i = bid * 256 + threadIdx.x;
        const float* src; short* dst; int j;
        if (i < 196608)      { src = s0; dst = d0; j = i; }
        else if (i < 262144) { src = s1; dst = d1; j = i - 196608; }
        else if (i < 524288) { src = s2; dst = d2; j = i - 262144; }
        else                 { src = s3; dst = d3; j = i - 524288; }
        float4 v = ((const float4*)src)[j];
        short4 o;
        o.x = f2bf(v.x); o.y = f2bf(v.y); o.z = f2bf(v.z); o.w = f2bf(v.w);
        ((short4*)dst)[j] = o;
    } else {
        int row = (bid - 3072) * 4 + (threadIdx.x >> 6);
        int lane = threadIdx.x & 63;
        ln_row(x + (size_t)row * Dn, ln1_g, ln1_b, x2 + (size_t)row * Dn, lane);
    }
}

// ---------------- LN2: bf16 input (res1), bf16 output; one wave per row -------------
__global__ __launch_bounds__(256) void ln2_kernel(const short* __restrict__ xh,
                                                  const float* __restrict__ g,
                                                  const float* __restrict__ b,
                                                  short* __restrict__ y)
{
    int row = blockIdx.x * 4 + (threadIdx.x >> 6);
    int lane = threadIdx.x & 63;
    const short* xrow = xh + (size_t)row * Dn;
    short8 v = *(const short8*)(xrow + lane * 8);
    float f[8];
#pragma unroll
    for (int k = 0; k < 8; ++k) f[k] = bf2f(v[k]);
    float s = 0.f;
#pragma unroll
    for (int k = 0; k < 8; ++k) s += f[k];
#pragma unroll
    for (int off = 32; off >= 1; off >>= 1) s += __shfl_xor(s, off, 64);
    float mu = s * (1.0f / Dn);
    float q = 0.f;
#pragma unroll
    for (int k = 0; k < 8; ++k) { float d = f[k] - mu; q += d * d; }
#pragma unroll
    for (int off = 32; off >= 1; off >>= 1) q += __shfl_xor(q, off, 64);
    float inv = rsqrtf(q * (1.0f / Dn) + EPS);
    const float4* gr = (const float4*)g;
    const float4* br = (const float4*)b;
    float4 g0 = gr[2 * lane], g1 = gr[2 * lane + 1];
    float4 b0 = br[2 * lane], b1 = br[2 * lane + 1];
    float gg[8] = {g0.x, g0.y, g0.z, g0.w, g1.x, g1.y, g1.z, g1.w};
    float bb[8] = {b0.x, b0.y, b0.z, b0.w, b1.x, b1.y, b1.z, b1.w};
    short8 o;
#pragma unroll
    for (int k = 0; k < 8; ++k) o[k] = f2bf((f[k] - mu) * inv * gg[k] + bb[k]);
    *(short8*)(y + (size_t)row * Dn + lane * 8) = o;
}

// ------- gemm_res: 64x128 tile, BK=64, double-buffered, 2 blocks/CU ----
// RIN: 0 = resid f32, 1 = resid bf16. OUT: 0 = f32 direct, 1 = bf16 via LDS repack.
template <int RIN, int OUT>
__global__ __launch_bounds__(256) void gemm_res(const short* __restrict__ A,
                                                const short* __restrict__ Bw,
                                                const float* __restrict__ bias,
                                                const void* __restrict__ resid,
                                                void* __restrict__ Cout,
                                                int M, int N, int K)
{
    constexpr int BK = 64;
    constexpr int ABUF = 64 * BK;               // 4096 shorts
    constexpr int BBUF = 128 * BK;              // 8192 shorts
    __shared__ short SMEM[2 * (ABUF + BBUF)];   // 48 KB
    short* Asb = SMEM;
    short* Bsb = SMEM + 2 * ABUF;

    int tid = threadIdx.x;
    int w = tid >> 6, lane = tid & 63;
    int wr = w >> 1, wc = w & 1;                // wave tile 32m x 64n
    int nN = N >> 7;
    int bid = blockIdx.x;
    int xcd = bid & 7, sq = bid >> 3;
    int mi = xcd + 8 * (sq / nN);
    int ni = sq % nN;
    int m0 = mi * 64, n0 = ni * 128;
    int quad = lane >> 4, l16 = lane & 15;

    f32x4 zero = {0.f, 0.f, 0.f, 0.f};
    f32x4 acc[2][4];
#pragma unroll
    for (int i = 0; i < 2; ++i)
#pragma unroll
        for (int j = 0; j < 4; ++j) acc[i][j] = zero;

    int rl = lane >> 3;                          // 0..7
    int ch = lane & 7;
    const short* Ag[2];
    const short* Bg[4];
    int aOff[2], bOff[4];
#pragma unroll
    for (int s = 0; s < 2; ++s) {
        int rowl = w * 16 + s * 8 + rl;
        int csw = (ch ^ (rowl & 7)) * 8;
        Ag[s] = A + (size_t)(m0 + rowl) * K + csw;
        aOff[s] = (w * 16 + s * 8) * BK;
    }
#pragma unroll
    for (int s = 0; s < 4; ++s) {
        int rowl = w * 32 + s * 8 + rl;
        int csw = (ch ^ (rowl & 7)) * 8;
        Bg[s] = Bw + (size_t)(n0 + rowl) * K + csw;
        bOff[s] = (w * 32 + s * 8) * BK;
    }

    auto stage = [&](int kt, int pp) {
#pragma unroll
        for (int s = 0; s < 2; ++s)
            async16(Ag[s] + kt, Asb + pp * ABUF + aOff[s]);
#pragma unroll
        for (int s = 0; s < 4; ++s)
            async16(Bg[s] + kt, Bsb + pp * BBUF + bOff[s]);
    };

    stage(0, 0);
    int p = 0;
    for (int kt = 0; kt < K; kt += BK) {
        __syncthreads();
        if (kt + BK < K) stage(kt + BK, p ^ 1);
        short8 aF[2][2], bF[2][4];
#pragma unroll
        for (int kk = 0; kk < 2; ++kk) {
#pragma unroll
            for (int i = 0; i < 2; ++i) {
                int ra = wr * 32 + i * 16 + l16;
                int cs = ((kk * 4 + quad) ^ (ra & 7)) * 8;
                aF[kk][i] = *(const short8*)(Asb + p * ABUF + ra * BK + cs);
            }
#pragma unroll
            for (int j = 0; j < 4; ++j) {
                int rb = wc * 64 + j * 16 + l16;
                int cs = ((kk * 4 + quad) ^ (rb & 7)) * 8;
                bF[kk][j] = *(const short8*)(Bsb + p * BBUF + rb * BK + cs);
            }
        }
#pragma unroll
        for (int kk = 0; kk < 2; ++kk)
#pragma unroll
            for (int i = 0; i < 2; ++i)
#pragma unroll
                for (int j = 0; j < 4; ++j)
                    acc[i][j] = __builtin_amdgcn_mfma_f32_16x16x32_bf16(
                        aF[kk][i], bF[kk][j], acc[i][j], 0, 0, 0);
        p ^= 1;
    }

    const float* rf = (const float*)resid;
    const short* rh = (const short*)resid;

    if constexpr (OUT == 0) {
        float* Cf = (float*)Cout;
#pragma unroll
        for (int j = 0; j < 4; ++j) {
            int n = n0 + wc * 64 + j * 16 + l16;
            float bv = bias[n];
#pragma unroll
            for (int i = 0; i < 2; ++i) {
                int mbase = m0 + wr * 32 + i * 16 + quad * 4;
#pragma unroll
                for (int r = 0; r < 4; ++r) {
                    size_t idx = (size_t)(mbase + r) * N + n;
                    float rv = RIN ? bf2f(rh[idx]) : rf[idx];
                    Cf[idx] = acc[i][j][r] + bv + rv;
                }
            }
        }
    } else {
        // bf16 out via LDS repack (full-line short8 stores)
        __syncthreads();
        short* rp = SMEM + w * 6144;             // 32 x 72 needed = 2304
#pragma unroll
        for (int j = 0; j < 4; ++j) {
            int n = n0 + wc * 64 + j * 16 + l16;
            float bv = bias[n];
#pragma unroll
            for (int i = 0; i < 2; ++i) {
                int ml = i * 16 + quad * 4;
#pragma unroll
                for (int r = 0; r < 4; ++r) {
                    size_t idx = (size_t)(m0 + wr * 32 + ml + r) * N + n;
                    float rv = RIN ? bf2f(rh[idx]) : rf[idx];
                    rp[(ml + r) * 72 + j * 16 + l16] = f2bf(acc[i][j][r] + bv + rv);
                }
            }
        }
        short* Cb = (short*)Cout;
#pragma unroll
        for (int it = 0; it < 4; ++it) {
            int row = it * 8 + (lane >> 3);
            int off = (lane & 7) * 8;
            *(short8*)(Cb + (size_t)(m0 + wr * 32 + row) * N + n0 + wc * 64 + off) =
                *(const short8*)(rp + row * 72 + off);
        }
    }
}

// ---------------- QKV GEMM: 64x256 tile, BK=32, wave 32x128; grid 768 = 3/CU --------
__global__ __launch_bounds__(256, 3) void gemm_qkv(const short* __restrict__ A,
                                                   const short* __restrict__ Bw,
                                                   const float* __restrict__ bias,
                                                   short* __restrict__ q_out,
                                                   short* __restrict__ k_out,
                                                   short* __restrict__ v_out,
                                                   int M, int N, int K)
{
    constexpr int BK = 32;
    constexpr int ABUF = 64 * BK;               // 2048 shorts
    constexpr int BBUF = 256 * BK;              // 8192 shorts
    __shared__ short SMEM[2 * (ABUF + BBUF)];   // 20480 shorts = 40 KB
    short* Asb = SMEM;
    short* Bsb = SMEM + 2 * ABUF;

    int tid = threadIdx.x;
    int w = tid >> 6, lane = tid & 63;
    int wr = w >> 1, wc = w & 1;                // wave tile 32m x 128n
    int nT = N >> 8;                            // 6
    int bid = blockIdx.x;
    int xcd = bid & 7, sq = bid >> 3;
    int mi = xcd + 8 * (sq / nT);
    int ni = sq % nT;
    int m0 = mi * 64, n0 = ni * 256;
    int quad = lane >> 4, l16 = lane & 15;

    f32x4 zero = {0.f, 0.f, 0.f, 0.f};
    f32x4 acc[2][8];
#pragma unroll
    for (int i = 0; i < 2; ++i)
#pragma unroll
        for (int j = 0; j < 8; ++j) acc[i][j] = zero;

    int rl = lane >> 2;                          // 0..15
    int ch = lane & 3;
    const short* Ag;
    const short* Bg[4];
    int aOff, bOff[4];
    {
        int rowl = w * 16 + rl;
        int csw = (ch ^ ((rowl >> 1) & 3)) * 8;
        Ag = A + (size_t)(m0 + rowl) * K + csw;
        aOff = (w * 16) * BK;
    }
#pragma unroll
    for (int s = 0; s < 4; ++s) {
        int rowl = w * 64 + s * 16 + rl;
        int csw = (ch ^ ((rowl >> 1) & 3)) * 8;
        Bg[s] = Bw + (size_t)(n0 + rowl) * K + csw;
        bOff[s] = (w * 64 + s * 16) * BK;
    }

    auto stage = [&](int kt, int pp) {
        async16(Ag + kt, Asb + pp * ABUF + aOff);
#pragma unroll
        for (int s = 0; s < 4; ++s)
            async16(Bg[s] + kt, Bsb + pp * BBUF + bOff[s]);
    };

    int aoff[2], boff[8];
#pragma unroll
    for (int i = 0; i < 2; ++i) {
        int ra = wr * 32 + i * 16 + l16;
        aoff[i] = ra * BK + (quad ^ ((ra >> 1) & 3)) * 8;
    }
#pragma unroll
    for (int j = 0; j < 8; ++j) {
        int rb = wc * 128 + j * 16 + l16;
        boff[j] = rb * BK + (quad ^ ((rb >> 1) & 3)) * 8;
    }

    stage(0, 0);
    int p = 0;
    for (int kt = 0; kt < K; kt += BK) {
        __syncthreads();
        if (kt + BK < K) stage(kt + BK, p ^ 1);
        short8 aF[2], bF[8];
#pragma unroll
        for (int i = 0; i < 2; ++i)
            aF[i] = *(const short8*)(Asb + p * ABUF + aoff[i]);
#pragma unroll
        for (int j = 0; j < 8; ++j)
            bF[j] = *(const short8*)(Bsb + p * BBUF + boff[j]);
#pragma unroll
        for (int i = 0; i < 2; ++i)
#pragma unroll
            for (int j = 0; j < 8; ++j)
                acc[i][j] = __builtin_amdgcn_mfma_f32_16x16x32_bf16(
                    aF[i], bF[j], acc[i][j], 0, 0, 0);
        p ^= 1;
    }

    __syncthreads();                             // K-loop LDS dead -> repack
    short* rp = SMEM + w * 5120;                 // per-wave slot (5120 shorts)
    float bv[8];
#pragma unroll
    for (int j = 0; j < 8; ++j) bv[j] = bias[n0 + wc * 128 + j * 16 + l16];

    int b = m0 >> 11;
    int ncol0 = n0 + wc * 128;
    int sec = ncol0 >> 9;                        // 0=q 1=k 2=v (128-slice never crosses)
    int h0 = (ncol0 & 511) >> 6;                 // heads h0, h0+1
    int t0 = (m0 & 2047) + wr * 32;

    if (sec == 2) {
#pragma unroll
        for (int ph = 0; ph < 2; ++ph) {
#pragma unroll
            for (int j = 4 * ph; j < 4 * ph + 4; ++j) {
                int d = (j - 4 * ph) * 16 + l16;
#pragma unroll
                for (int i = 0; i < 2; ++i)
#pragma unroll
                    for (int r = 0; r < 4; ++r)
                        rp[d * 40 + i * 16 + quad * 4 + r] = f2bf(acc[i][j][r] + bv[j]);
            }
            int bh = b * 8 + h0 + ph;
#pragma unroll
            for (int it = 0; it < 4; ++it) {
                int drow = it * 16 + (lane >> 2);        // 0..63
                int toff = (lane & 3) * 8;               // 0..24
                *(short8*)(v_out + ((size_t)bh * 64 + drow) * 2048 + t0 + toff) =
                    *(const short8*)(rp + drow * 40 + toff);
            }
        }
    } else {
        short* dst = (sec == 0 ? q_out : k_out);
#pragma unroll
        for (int i = 0; i < 2; ++i) {
            int tl = i * 16 + quad * 4;
#pragma unroll
            for (int j = 0; j < 8; ++j)
#pragma unroll
                for (int r = 0; r < 4; ++r)
                    rp[(tl + r) * 136 + j * 16 + l16] = f2bf(acc[i][j][r] + bv[j]);
        }
#pragma unroll
        for (int it = 0; it < 8; ++it) {
            int trow = it * 4 + (lane >> 4);             // 0..31
            int hh = (lane & 15) >> 3;                   // head select
            int off = (lane & 7) * 8;                    // d chunk
            int bh = b * 8 + h0 + hh;
            *(short8*)(dst + ((size_t)bh * 2048 + t0 + trow) * 64 + off) =
                *(const short8*)(rp + trow * 136 + hh * 64 + off);
        }
    }
}

// ---------------- FFN1 GEMM: 128x128 tile, BK=32, 32KB LDS, grid 1024 ---------------
__global__ __launch_bounds__(256) void gemm_ffn1(const short* __restrict__ A,
                                                 const short* __restrict__ Bw,
                                                 const float* __restrict__ bias,
                                                 short* __restrict__ Cb,
                                                 int M, int N, int K)
{
    constexpr int BK = 32;
    constexpr int BUF = 128 * BK;               // 4096 shorts
    __shared__ short SMEM[4 * BUF];             // 32 KB; repack aliases
    short* Asb = SMEM;
    short* Bsb = SMEM + 2 * BUF;

    int tid = threadIdx.x;
    int w = tid >> 6, lane = tid & 63;
    int wr = w >> 1, wc = w & 1;                // wave tile 64m x 64n
    int nN = N >> 7;                            // 16
    int bid = blockIdx.x;
    int xcd = bid & 7, sq = bid >> 3;
    int mi = xcd + 8 * (sq / nN);
    int ni = sq % nN;
    int m0 = mi * 128, n0 = ni * 128;
    int quad = lane >> 4, l16 = lane & 15;

    f32x4 zero = {0.f, 0.f, 0.f, 0.f};
    f32x4 acc[4][4];
#pragma unroll
    for (int i = 0; i < 4; ++i)
#pragma unroll
        for (int j = 0; j < 4; ++j) acc[i][j] = zero;

    int rl = lane >> 2;                          // 0..15
    int ch = lane & 3;
    const short* Ag[2];
    const short* Bg[2];
    int ldsOff[2];
#pragma unroll
    for (int s = 0; s < 2; ++s) {
        int rowl = w * 32 + s * 16 + rl;
        int csw = (ch ^ ((rowl >> 1) & 3)) * 8;
        Ag[s] = A + (size_t)(m0 + rowl) * K + csw;
        Bg[s] = Bw + (size_t)(n0 + rowl) * K + csw;
        ldsOff[s] = (w * 32 + s * 16) * BK;
    }

    auto stage = [&](int kt, int pp) {
#pragma unroll
        for (int s = 0; s < 2; ++s) {
            async16(Ag[s] + kt, Asb + pp * BUF + ldsOff[s]);
            async16(Bg[s] + kt, Bsb + pp * BUF + ldsOff[s]);
        }
    };

    int aoff[4], boff[4];
#pragma unroll
    for (int i = 0; i < 4; ++i) {
        int ra = wr * 64 + i * 16 + l16;
        int rb = wc * 64 + i * 16 + l16;
        aoff[i] = ra * BK + (quad ^ ((ra >> 1) & 3)) * 8;
        boff[i] = rb * BK + (quad ^ ((rb >> 1) & 3)) * 8;
    }

    stage(0, 0);
    int p = 0;
    for (int kt = 0; kt < K; kt += BK) {
        __syncthreads();
        if (kt + BK < K) stage(kt + BK, p ^ 1);
        short8 aF[4], bF[4];
#pragma unroll
        for (int i = 0; i < 4; ++i) {
            aF[i] = *(const short8*)(Asb + p * BUF + aoff[i]);
            bF[i] = *(const short8*)(Bsb + p * BUF + boff[i]);
        }
#pragma unroll
        for (int i = 0; i < 4; ++i)
#pragma unroll
            for (int j = 0; j < 4; ++j)
                acc[i][j] = __builtin_amdgcn_mfma_f32_16x16x32_bf16(
                    aF[i], bF[j], acc[i][j], 0, 0, 0);
        p ^= 1;
    }

    __syncthreads();                            // K-loop LDS dead -> repack
    short* rp = SMEM + w * 2176;                // 32 x 68 per phase
#pragma unroll
    for (int ph = 0; ph < 2; ++ph) {
#pragma unroll
        for (int i = 2 * ph; i < 2 * ph + 2; ++i) {
            int ml = (i - 2 * ph) * 16 + quad * 4;
#pragma unroll
            for (int j = 0; j < 4; ++j) {
                float bv = bias[n0 + wc * 64 + j * 16 + l16];
#pragma unroll
                for (int r = 0; r < 4; ++r)
                    rp[(ml + r) * 68 + j * 16 + l16] =
                        f2bf(gelu_fast(acc[i][j][r] + bv));
            }
        }
#pragma unroll
        for (int it = 0; it < 4; ++it) {
            int row = it * 8 + (lane >> 3);            // m local
            int off = (lane & 7) * 8;                  // n chunk
            *(short8*)(Cb + (size_t)(m0 + wr * 64 + 32 * ph + row) * N
                          + n0 + wc * 64 + off) =
                *(const short8*)(rp + row * 68 + off);
        }
    }
}

// ---------------- MFMA sliding-window attention (fully async-staged) ----------------
// One block: one (b,h), 64-query tile. Keys [q0-128, q0+64) = 192.
// Qg/Kg: [bh][t][64] bf16; Vtg: [bh][64][2048] bf16 (dim-major). ctx: (B,T,512) bf16.
// Q/K: unpadded 64-short rows, chunk XOR swizzle (c ^= row&7) -> <=2-way banks.
// V: unpadded [64][192], rotation swizzle p=(c+row)%24 -> 2-way banks (free, m136);
//    staged by 24 async16 instrs with per-lane gather (r=f/24, c=(p-r)%24, clamp).
constexpr int PS = 200;   // Ps LDS row stride (shorts)

__global__ __launch_bounds__(256) void attn_mfma(const short* __restrict__ Qg,
                                                 const short* __restrict__ Kg,
                                                 const short* __restrict__ Vtg,
                                                 short* __restrict__ ctx)
{
    // LDS layout (shorts):
    //   [0, 4096)      Qs 64x64 swizzled   } dead after S-loop
    //   [4096, 16384)  Ks 192x64 swizzled  } dead after S-loop
    //   [0, 12800)     Ps 64xPS (aliases Qs/Ks after barrier)
    //   [16384, 28672) Vt 64x192 rotation-swizzled
    __shared__ short SM[28672];
    short* Qs = SM;
    short* Ks = SM + 4096;
    short* Vt = SM + 16384;
    short* Ps = SM;

    int tid = threadIdx.x;
    int w = tid >> 6, lane = tid & 63, quad = lane >> 4, l16 = lane & 15;
    int blk = blockIdx.x;
    int q0 = (blk & 31) << 6;
    int bh = blk >> 5;
    int kbase = q0 - 128;

    // async stage Q (2 instrs/wave) and K (6 instrs/wave)
    {
        int r8 = lane >> 3, lc = lane & 7;
        const short* qb = Qg + ((size_t)bh * 2048 + q0) * 64;
#pragma unroll
        for (int s = 0; s < 2; ++s) {
            int rowbase = w * 16 + s * 8;
            int row = rowbase + r8;
            int gc = lc ^ (row & 7);
            async16(qb + (size_t)row * 64 + gc * 8, Qs + rowbase * 64);
        }
        const short* kb = Kg + (size_t)bh * 2048 * 64;
#pragma unroll
        for (int s = 0; s < 6; ++s) {
            int rowbase = w * 48 + s * 8;
            int row = rowbase + r8;
            int gc = lc ^ (row & 7);
            int srow = kbase + row; srow = srow < 0 ? 0 : srow;
            async16(kb + (size_t)srow * 64 + gc * 8, Ks + rowbase * 64);
        }
    }
    // async stage Vt (6 instrs/wave): physical slot f = instr*64 + lane,
    // r = f/24, p = f%24, logical chunk c = (p - r) mod 24, gather with clamp.
    {
        const short* base = Vtg + (size_t)bh * 64 * 2048;
#pragma unroll
        for (int s = 0; s < 6; ++s) {
            int iid = w * 6 + s;                 // 0..23
            int f = iid * 64 + lane;             // 0..1535
            int r = f / 24;
            int p = f - r * 24;
            int rm = r % 24;
            int c = p - rm; if (c < 0) c += 24;
            int scol = kbase + c * 8; if (scol < 0) scol = 0;
            async16(base + (size_t)r * 2048 + scol, Vt + iid * 512);
        }
    }
    __syncthreads();   // drains vmcnt (all async staging)

    int qrow = w * 16 + l16;
    short8 aF0 = *(const short8*)(Qs + qrow * 64 + ((quad ^ (qrow & 7)) * 8));
    short8 aF1 = *(const short8*)(Qs + qrow * 64 + (((4 + quad) ^ (qrow & 7)) * 8));
    f32x4 S[12];
    f32x4 zero = {0.f, 0.f, 0.f, 0.f};
#pragma unroll
    for (int t = 0; t < 12; ++t) S[t] = zero;
#pragma unroll
    for (int t = 0; t < 12; ++t) {
        int krow = t * 16 + l16;
        short8 b0 = *(const short8*)(Ks + krow * 64 + ((quad ^ (krow & 7)) * 8));
        short8 b1 = *(const short8*)(Ks + krow * 64 + (((4 + quad) ^ (krow & 7)) * 8));
        S[t] = __builtin_amdgcn_mfma_f32_16x16x32_bf16(aF0, b0, S[t], 0, 0, 0);
        S[t] = __builtin_amdgcn_mfma_f32_16x16x32_bf16(aF1, b1, S[t], 0, 0, 0);
    }

    int i0 = w * 16 + quad * 4;
    float mrow[4] = {-INFINITY, -INFINITY, -INFINITY, -INFINITY};
#pragma unroll
    for (int t = 0; t < 12; ++t) {
        int jl = t * 16 + l16;
        int kg = kbase + jl;
#pragma unroll
        for (int r = 0; r < 4; ++r) {
            int dj = jl - (i0 + r);
            bool ok = (dj >= 1) && (dj <= 128) && (kg >= 0);
            float s = ok ? S[t][r] * 0.125f : -INFINITY;
            S[t][r] = s;
            mrow[r] = fmaxf(mrow[r], s);
        }
    }
#pragma unroll
    for (int off = 8; off >= 1; off >>= 1)
#pragma unroll
        for (int r = 0; r < 4; ++r)
            mrow[r] = fmaxf(mrow[r], __shfl_xor(mrow[r], off, 64));
    float sum[4] = {0.f, 0.f, 0.f, 0.f};
#pragma unroll
    for (int t = 0; t < 12; ++t)
#pragma unroll
        for (int r = 0; r < 4; ++r) {
            float p = __expf(S[t][r] - mrow[r]);
            S[t][r] = p;
            sum[r] += p;
        }
#pragma unroll
    for (int off = 8; off >= 1; off >>= 1)
#pragma unroll
        for (int r = 0; r < 4; ++r)
            sum[r] += __shfl_xor(sum[r], off, 64);
    float inv[4];
#pragma unroll
    for (int r = 0; r < 4; ++r) inv[r] = 1.0f / sum[r];

    __syncthreads();   // all waves done reading Qs/Ks -> alias as Ps
#pragma unroll
    for (int t = 0; t < 12; ++t)
#pragma unroll
        for (int r = 0; r < 4; ++r)
            Ps[(w * 16 + quad * 4 + r) * PS + t * 16 + l16] = f2bf(S[t][r]);
    // same-wave write->read: compiler inserts lgkmcnt wait; no barrier needed

    f32x4 O[4];
#pragma unroll
    for (int tN = 0; tN < 4; ++tN) O[tN] = zero;
    int rb24[4];
#pragma unroll
    for (int tN = 0; tN < 4; ++tN) rb24[tN] = (tN * 16 + l16) % 24;
#pragma unroll
    for (int s = 0; s < 6; ++s) {
        short8 aP = *(const short8*)(Ps + (w * 16 + l16) * PS + s * 32 + quad * 8);
#pragma unroll
        for (int tN = 0; tN < 4; ++tN) {
            int rb = tN * 16 + l16;
            int pc = s * 4 + quad + rb24[tN]; if (pc >= 24) pc -= 24;
            short8 bV = *(const short8*)(Vt + rb * 192 + pc * 8);
            O[tN] = __builtin_amdgcn_mfma_f32_16x16x32_bf16(aP, bV, O[tN], 0, 0, 0);
        }
    }

    int b = bh >> 3, h = bh & 7;
#pragma unroll
    for (int tN = 0; tN < 4; ++tN)
#pragma unroll
        for (int r = 0; r < 4; ++r) {
            int trow = q0 + w * 16 + quad * 4 + r;
            ctx[((size_t)(b * 2048 + trow)) * 512 + h * 64 + tN * 16 + l16] =
                f2bf(O[tN][r] * inv[r]);
        }
}

extern "C" void kernel_launch(void* const* d_in, const int* in_sizes, int n_in,
                              void* d_out, int out_size, void* d_ws, size_t ws_size,
                              hipStream_t stream)
{
    const float* x         = (const float*)d_in[0];
    const float* in_proj_w = (const float*)d_in[1];
    const float* in_proj_b = (const float*)d_in[2];
    const float* out_w     = (const float*)d_in[3];
    const float* out_b     = (const float*)d_in[4];
    const float* ln1_g     = (const float*)d_in[5];
    const float* ln1_b     = (const float*)d_in[6];
    const float* ln2_g     = (const float*)d_in[7];
    const float* ln2_b     = (const float*)d_in[8];
    const float* w1        = (const float*)d_in[9];
    const float* b1        = (const float*)d_in[10];
    const float* w2        = (const float*)d_in[11];
    const float* b2        = (const float*)d_in[12];
    float* out = (float*)d_out;

    // ws layout:
    //   0-32 MB : attnQ/K/V (8 MB each) -> later hbuf (32 MB)
    //   32-40   : regB (x2 / ctx / x3 bf16)
    //   40-46.3 : bf16 weights
    //   48-56   : res1 (bf16 residual after attention)
    char* ws = (char*)d_ws;
    short* attnQ = (short*)ws;
    short* attnK = (short*)(ws + (size_t)8 * 1024 * 1024);
    short* attnV = (short*)(ws + (size_t)16 * 1024 * 1024);
    short* hbuf  = (short*)ws;
    short* regB  = (short*)(ws + (size_t)32 * 1024 * 1024);
    short* wq  = (short*)(ws + (size_t)40 * 1024 * 1024);
    short* wo  = wq + (size_t)QKVD * Dn;
    short* w1b = wo + (size_t)Dn * Dn;
    short* w2b = w1b + (size_t)Fn * Dn;
    short* res1 = (short*)(ws + (size_t)48 * 1024 * 1024);

    // 0+1) weight cvt + LN1 fused
    prep_kernel<<<5120, 256, 0, stream>>>(in_proj_w, out_w, w1, w2, wq, wo, w1b, w2b,
                                          x, ln1_g, ln1_b, regB);
    // 2) qkv = x2 @ in_proj_w^T + b -> bf16 attention layouts (64x256 tiles, 3/CU)
    gemm_qkv<<<(Mrows / 64) * (QKVD / 256), 256, 0, stream>>>(
        regB, wq, in_proj_b, attnQ, attnK, attnV, Mrows, QKVD, Dn);
    // 3) ctx = attention -> bf16 (B,T,512)
    attn_mfma<<<Bn * Hn * (Tn / 64), 256, 0, stream>>>(attnQ, attnK, attnV, regB);
    // 4) res1 = bf16(x + ctx @ out_w^T + out_b)
    gemm_res<0, 1><<<(Mrows / 64) * (Dn / 128), 256, 0, stream>>>(
        regB, wo, out_b, x, res1, Mrows, Dn, Dn);
    // 5) x3 = LN2(res1) -> bf16
    ln2_kernel<<<Mrows / 4, 256, 0, stream>>>(res1, ln2_g, ln2_b, regB);
    // 6) h = gelu(x3 @ w1^T + b1) -> bf16 (128x128 tiles, grid 1024)
    gemm_ffn1<<<(Mrows / 128) * (Fn / 128), 256, 0, stream>>>(
        regB, w1b, b1, hbuf, Mrows, Fn, Dn);
    // 7) out = res1 + h @ w2^T + b2 -> f32
    gemm_res<1, 0><<<(Mrows / 64) * (Dn / 128), 256, 0, stream>>>(
        hbuf, w2b, b2, res1, out, Mrows, Dn, Fn);
}